// Round 3
// baseline (686.602 us; speedup 1.0000x reference)
//
#include <hip/hip_runtime.h>

// Problem constants (B, L, H, D) = (4, 4096, 8, 64), FACTOR=5
// Inputs/outputs are float32 per the reference (jnp.float32).
#define NB 4
#define LSEQ 4096
#define NH 8
#define ND 64
#define NSAMP 45
#define NTOP 45

typedef float f32x4 __attribute__((ext_vector_type(4)));

// ---------------------------------------------------------------------------
// Kernel 1: M[b,h,l] = max_s(q.k_s) - sum_s(q.k_s)/LSEQ over 45 sampled keys.
// Round-8: 16-LANE-COOPERATIVE rows. Each 16-lane group owns one (b,h,l):
// lane r holds dims 4r..4r+3 (one float4). The original per-thread butterfly
// add tree maps EXACTLY onto shfl_xor stages (off=32 -> xor8 on products,
// off=16 -> xor4, off=8 -> xor2, off=4 -> xor1, off=2/1 in-lane), with every
// __fadd_rn keeping the same operand PAIRING -> bit-identical M -> selection
// frozen. Benefits vs round-7 (which spilled: VGPR=128 + 43MB scratch):
//  * one K row in flight = 4 VGPRs (not 64) -> 6-deep pipeline costs 24 regs,
//    no spill, ~8 loads in flight per group;
//  * each row fetch is ONE coalesced 256B wave-instruction;
//  * occupancy grid 2048 blocks, VGPR ~<=64 -> up to 8 waves/SIMD.
// XCD pinning kept: blockIdx&7 -> 4 (b,h) pairs = 4MB K working set = L2.
// ---------------------------------------------------------------------------
__global__ __launch_bounds__(256) void compute_M_kernel(
        const float* __restrict__ Q,
        const float* __restrict__ K,
        const int* __restrict__ idxS,
        float* __restrict__ Mout) {
    int xcd = blockIdx.x & 7;          // XCD slot (round-robin dispatch)
    int sub = blockIdx.x >> 3;         // 0..255
    int bh  = (xcd << 2) | (sub & 3);  // 4 bh per XCD -> 4MB L2 working set
    int lchunk = sub >> 2;             // 0..63
    int b = bh >> 3, h = bh & 7;
    int t = threadIdx.x;
    int g = t >> 4, r = t & 15;        // 16 groups x 16 lanes

    size_t kbase = ((size_t)b * LSEQ * NH + h) * ND + (size_t)(r * 4);

    #pragma unroll 1
    for (int it = 0; it < 4; ++it) {
        int l = (lchunk << 6) | (it << 4) | g;
        const int* is = idxS + (size_t)l * NSAMP;
        // Q row: one float4 per lane, nontemporal (one-shot stream; keep L2
        // for the K gather residency).
        f32x4 q = __builtin_nontemporal_load(
            reinterpret_cast<const f32x4*>(
                Q + (((size_t)b * LSEQ + l) * NH + h) * ND) + r);

        constexpr int PD = 6;          // samples in flight per group
        f32x4 kr[PD];
        #pragma unroll
        for (int p = 0; p < PD; ++p)
            kr[p] = *reinterpret_cast<const f32x4*>(
                K + kbase + (size_t)is[p] * (NH * ND));

        float maxv = -INFINITY;
        float sumv = 0.0f;

        #pragma unroll
        for (int s = 0; s < NSAMP; ++s) {
            f32x4 k = kr[s % PD];
            if (s + PD < NSAMP)
                kr[s % PD] = *reinterpret_cast<const f32x4*>(
                    K + kbase + (size_t)is[s + PD] * (NH * ND));

            // products p[d] (same __fmul_rn as scalar version)
            float p0 = __fmul_rn(q.x, k.x);
            float p1 = __fmul_rn(q.y, k.y);
            float p2 = __fmul_rn(q.z, k.z);
            float p3 = __fmul_rn(q.w, k.w);
            // stage off=32: pair lanes r, r^8 (products) — commutative fadd
            float w0 = __fadd_rn(p0, __shfl_xor(p0, 8, 64));
            float w1 = __fadd_rn(p1, __shfl_xor(p1, 8, 64));
            float w2 = __fadd_rn(p2, __shfl_xor(p2, 8, 64));
            float w3 = __fadd_rn(p3, __shfl_xor(p3, 8, 64));
            // stage off=16: lanes r, r^4
            w0 = __fadd_rn(w0, __shfl_xor(w0, 4, 64));
            w1 = __fadd_rn(w1, __shfl_xor(w1, 4, 64));
            w2 = __fadd_rn(w2, __shfl_xor(w2, 4, 64));
            w3 = __fadd_rn(w3, __shfl_xor(w3, 4, 64));
            // stage off=8: lanes r, r^2
            w0 = __fadd_rn(w0, __shfl_xor(w0, 2, 64));
            w1 = __fadd_rn(w1, __shfl_xor(w1, 2, 64));
            w2 = __fadd_rn(w2, __shfl_xor(w2, 2, 64));
            w3 = __fadd_rn(w3, __shfl_xor(w3, 2, 64));
            // stage off=4: lanes r, r^1
            w0 = __fadd_rn(w0, __shfl_xor(w0, 1, 64));
            w1 = __fadd_rn(w1, __shfl_xor(w1, 1, 64));
            w2 = __fadd_rn(w2, __shfl_xor(w2, 1, 64));
            w3 = __fadd_rn(w3, __shfl_xor(w3, 1, 64));
            // stages off=2, off=1 (in-lane, exact original pairing)
            float pr = __fadd_rn(__fadd_rn(w0, w2), __fadd_rn(w1, w3));

            maxv = fmaxf(maxv, pr);
            sumv = __fadd_rn(sumv, pr);
        }
        if (r == 0)
            Mout[(size_t)bh * LSEQ + l] = maxv - sumv * (1.0f / (float)LSEQ);
    }
}

// ---------------------------------------------------------------------------
// Kernel 2: top-45 per (b,h). UNCHANGED (selection semantics frozen).
// ---------------------------------------------------------------------------
__global__ __launch_bounds__(256) void topk_kernel(
        const float* __restrict__ M, int* __restrict__ Mtop) {
    int bh = blockIdx.x;
    int t = threadIdx.x;
    int wave = t >> 6, lane = t & 63;
    const float* m = M + (size_t)bh * LSEQ;

    float rv[16];
    #pragma unroll
    for (int k = 0; k < 16; ++k) rv[k] = m[t + (k << 8)];

    __shared__ float wv[4];
    __shared__ int   wi[4];
    __shared__ int   winIdx;

    for (int iter = 0; iter < NTOP; ++iter) {
        float bv = -INFINITY; int bi = 0x7fffffff;
        #pragma unroll
        for (int k = 0; k < 16; ++k) {
            float v = rv[k];
            if (v > bv) { bv = v; bi = t + (k << 8); }
        }
        #pragma unroll
        for (int off = 1; off < 64; off <<= 1) {
            float ov = __shfl_xor(bv, off, 64);
            int   oi = __shfl_xor(bi, off, 64);
            if (ov > bv || (ov == bv && oi < bi)) { bv = ov; bi = oi; }
        }
        if (lane == 0) { wv[wave] = bv; wi[wave] = bi; }
        __syncthreads();
        if (t == 0) {
            float cv = wv[0]; int ci = wi[0];
            for (int ww = 1; ww < 4; ++ww) {
                if (wv[ww] > cv || (wv[ww] == cv && wi[ww] < ci)) { cv = wv[ww]; ci = wi[ww]; }
            }
            winIdx = ci;
            Mtop[bh * NTOP + iter] = ci;
        }
        __syncthreads();
        int widx = winIdx;
        #pragma unroll
        for (int k = 0; k < 16; ++k)
            if (widx == t + (k << 8)) rv[k] = -INFINITY;
        __syncthreads();
    }
}

// ---------------------------------------------------------------------------
// Kernel 3a: per-chunk sums of V (16 chunks of 256 rows per (b,h)).
// Grid 512 = (bh,c); 256 thr = 4 row-groups x 64 d. Reads 32 MB once.
// ---------------------------------------------------------------------------
__global__ __launch_bounds__(256) void cumsumA_kernel(
        const float* __restrict__ V, float* __restrict__ chunkSums) {
    int blk = blockIdx.x;
    int c = blk & 15;
    int bh = blk >> 4;
    int h = bh & (NH - 1);
    int b = bh >> 3;
    int g = threadIdx.x >> 6, d = threadIdx.x & 63;

    const size_t rstride = (size_t)NH * ND;   // 512
    size_t vbase = (size_t)b * LSEQ * rstride + (size_t)h * ND + d;

    int l0 = c * 256 + g * 64;
    float s = 0.0f;
    for (int l = l0; l < l0 + 64; ++l) s += V[vbase + (size_t)l * rstride];

    __shared__ float part[4][ND];
    part[g][d] = s;
    __syncthreads();
    if (threadIdx.x < ND)
        chunkSums[(size_t)blk * ND + d] =
            part[0][d] + part[1][d] + part[2][d] + part[3][d];
}

// ---------------------------------------------------------------------------
// Kernel 3b: rescan chunk with exclusive prefix from chunkSums, write out.
// Grid 512 = (bh,c); 256 thr = 4 row-groups x 64 d. Reads 32 MB + writes 32.
// ---------------------------------------------------------------------------
__global__ __launch_bounds__(256) void cumsumC_kernel(
        const float* __restrict__ V, const float* __restrict__ chunkSums,
        float* __restrict__ out) {
    int blk = blockIdx.x;
    int c = blk & 15;
    int bh = blk >> 4;
    int h = bh & (NH - 1);
    int b = bh >> 3;
    int g = threadIdx.x >> 6, d = threadIdx.x & 63;

    const size_t rstride = (size_t)NH * ND;
    size_t vbase = (size_t)b * LSEQ * rstride + (size_t)h * ND + d;

    // prefix over earlier chunks
    float run = 0.0f;
    for (int cc = 0; cc < c; ++cc)
        run += chunkSums[((size_t)bh * 16 + cc) * ND + d];

    // within-chunk group partials
    int l0 = c * 256 + g * 64;
    float s = 0.0f;
    for (int l = l0; l < l0 + 64; ++l) s += V[vbase + (size_t)l * rstride];
    __shared__ float part[4][ND];
    part[g][d] = s;
    __syncthreads();
    for (int gg = 0; gg < g; ++gg) run += part[gg][d];

    size_t obase = (size_t)bh * LSEQ * ND + d;
    for (int l = l0; l < l0 + 64; ++l) {
        run += V[vbase + (size_t)l * rstride];
        out[obase + (size_t)l * ND] = run;
    }
}

// ---------------------------------------------------------------------------
// Kernel 4: per (b,h,u) flash attention, LDS-tiled (body as round 6).
// blockIdx remapped so all 45 u-blocks of one (b,h) land on ONE XCD
// (round-robin heuristic) and share the K/V stream in that XCD's L2.
// ---------------------------------------------------------------------------
#define TJ 64
__global__ __launch_bounds__(256) void attn_rows_kernel(
        const float* __restrict__ Q,
        const float* __restrict__ K,
        const float* __restrict__ V,
        const int* __restrict__ Mtop,
        float* __restrict__ out) {
    int x = blockIdx.x;
    int xcd = x & 7;
    int slot = x >> 3;           // 0..179
    int grp = slot / NTOP;       // 0..3
    int u = slot % NTOP;
    int bh = grp * 8 + xcd;      // all u of this bh share an XCD
    int h = bh & (NH - 1);
    int b = bh >> 3;
    int pos = Mtop[bh * NTOP + u];
    int n = pos + 1;
    int t = threadIdx.x;
    int r = t >> 2, qt = t & 3;

    __shared__ float Ks[TJ][65];
    __shared__ float Vs[TJ][65];
    __shared__ float red[256];

    const size_t rstride = (size_t)NH * ND;   // 512
    size_t base = (size_t)b * LSEQ * rstride + (size_t)h * ND;

    float qreg[16];
    const float* qrow = Q + base + (size_t)pos * rstride + qt * 16;
    #pragma unroll
    for (int i = 0; i < 16; i += 4) {
        float4 v4 = *reinterpret_cast<const float4*>(qrow + i);
        qreg[i] = v4.x; qreg[i + 1] = v4.y; qreg[i + 2] = v4.z; qreg[i + 3] = v4.w;
    }

    float m = -INFINITY, s = 0.0f;
    float o[16];
    #pragma unroll
    for (int dd = 0; dd < 16; ++dd) o[dd] = 0.0f;

    int ntiles = (n + TJ - 1) / TJ;
    for (int tt = 0; tt < ntiles; ++tt) {
        int j0 = tt * TJ;
        __syncthreads();
        #pragma unroll
        for (int i = 0; i < 4; ++i) {
            int u16 = t + i * 256;
            int rr = u16 >> 4, cc = u16 & 15;
            int j = j0 + rr;
            int jc = (j < n) ? j : (n - 1);
            const float* rowk = K + base + (size_t)jc * rstride;
            float4 kv = *reinterpret_cast<const float4*>(rowk + cc * 4);
            Ks[rr][cc * 4 + 0] = kv.x; Ks[rr][cc * 4 + 1] = kv.y;
            Ks[rr][cc * 4 + 2] = kv.z; Ks[rr][cc * 4 + 3] = kv.w;
            const float* rowv = V + base + (size_t)jc * rstride;
            float4 vv = *reinterpret_cast<const float4*>(rowv + cc * 4);
            Vs[rr][cc * 4 + 0] = vv.x; Vs[rr][cc * 4 + 1] = vv.y;
            Vs[rr][cc * 4 + 2] = vv.z; Vs[rr][cc * 4 + 3] = vv.w;
        }
        __syncthreads();

        int j = j0 + r;
        float acc = 0.0f;
        #pragma unroll
        for (int dd = 0; dd < 16; ++dd)
            acc = fmaf(qreg[dd], Ks[r][qt * 16 + dd], acc);
        acc += __shfl_xor(acc, 1, 64);
        acc += __shfl_xor(acc, 2, 64);

        if (j < n) {
            float sc = acc * 0.125f;
            if (sc > m) {
                float alpha = __expf(m - sc);
                s *= alpha;
                #pragma unroll
                for (int dd = 0; dd < 16; ++dd) o[dd] *= alpha;
                m = sc;
            }
            float e = __expf(sc - m);
            s += e;
            #pragma unroll
            for (int dd = 0; dd < 16; ++dd)
                o[dd] = fmaf(e, Vs[r][qt * 16 + dd], o[dd]);
        }
    }
    __syncthreads();

    red[t] = m; __syncthreads();
    for (int sft = 128; sft; sft >>= 1) {
        if (t < sft) red[t] = fmaxf(red[t], red[t + sft]);
        __syncthreads();
    }
    float mstar = red[0]; __syncthreads();
    float a = __expf(m - mstar);

    red[t] = s * a; __syncthreads();
    for (int sft = 128; sft; sft >>= 1) {
        if (t < sft) red[t] += red[t + sft];
        __syncthreads();
    }
    float S = red[0]; __syncthreads();

    float* OB = &Ks[0][0];
    #pragma unroll
    for (int dd = 0; dd < 16; ++dd) OB[t * 16 + dd] = o[dd] * a;
    __syncthreads();

    if (t < ND) {
        int qtt = t >> 4, dd = t & 15;
        float tot = 0.0f;
        for (int k = 0; k < 64; ++k) tot += OB[(4 * k + qtt) * 16 + dd];
        out[((size_t)bh * LSEQ + pos) * ND + t] = tot / S;
    }
}

// ---------------------------------------------------------------------------
extern "C" void kernel_launch(void* const* d_in, const int* in_sizes, int n_in,
                              void* d_out, int out_size, void* d_ws, size_t ws_size,
                              hipStream_t stream) {
    const float* Q = (const float*)d_in[0];
    const float* K = (const float*)d_in[1];
    const float* V = (const float*)d_in[2];
    const int* idxS = (const int*)d_in[3];
    float* out = (float*)d_out;

    // M (fp32, 512 KB) lives in d_out — consumed by topk before cumsum
    // overwrites d_out. ws: Mtop (5760 B) @0, chunkSums (128 KB) @8192.
    float* Mbuf = (float*)d_out;
    int*   Mtop = (int*)d_ws;
    float* chunkSums = (float*)((char*)d_ws + 8192);

    // 2048 blocks: 16 groups x 4 l-iters = 64 rows per block.
    compute_M_kernel<<<2048, 256, 0, stream>>>(Q, K, idxS, Mbuf);
    topk_kernel<<<NB * NH, 256, 0, stream>>>(Mbuf, Mtop);
    cumsumA_kernel<<<NB * NH * 16, 256, 0, stream>>>(V, chunkSums);
    cumsumC_kernel<<<NB * NH * 16, 256, 0, stream>>>(V, chunkSums, out);
    attn_rows_kernel<<<NB * NH * NTOP, 256, 0, stream>>>(Q, K, V, Mtop, out);
}

// Round 4
// 564.642 us; speedup vs baseline: 1.2160x; 1.2160x over previous
//
#include <hip/hip_runtime.h>

// Problem constants (B, L, H, D) = (4, 4096, 8, 64), FACTOR=5
// Inputs/outputs are float32 per the reference (jnp.float32).
#define NB 4
#define LSEQ 4096
#define NH 8
#define ND 64
#define NSAMP 45
#define NTOP 45

typedef float f32x4 __attribute__((ext_vector_type(4)));

// ---------------------------------------------------------------------------
// Kernel 1: M[b,h,l] = max_s(q.k_s) - sum_s(q.k_s)/LSEQ over 45 sampled keys.
// Round-9: back to ONE THREAD per (b,h,l) scalar tree (2 instr per
// (row,sample) pair — the r8 16-lane shuffle tree cost 10) + the r8 XCD
// pinning that made K L2-resident (FETCH 667->57 MB). The r7 scalar
// double-buffer spilled (compiler clamped 128 VGPR, 43 MB scratch); fixes:
//  * __launch_bounds__(256, 1): min 1 wave/EU -> VGPR cap 512, so the
//    ~230-reg working set (q4[16] + ka[16] + kb[16] + tree temps) fits at
//    2 waves/SIMD with NO spill.
//  * sched_barrier(0) fences pin the issue order load(next) -> tree(cur) so
//    the scheduler can't sink prefetch loads into the tree (the r6 68-VGPR
//    latency-serial failure mode). 16 x 16B loads in flight per thread
//    during every tree.
// Arithmetic/sample order byte-identical to r6 -> M bit-identical ->
// selection frozen. Floor: 1.5 GB from L2 @ ~34.5 TB/s ~= 43 us.
// ---------------------------------------------------------------------------
__global__ __launch_bounds__(256, 1) void compute_M_kernel(
        const float* __restrict__ Q,
        const float* __restrict__ K,
        const int* __restrict__ idxS,
        float* __restrict__ Mout) {
    // 512 blocks. xcd-slot = blockIdx&7 -> (b, h-half); slot = blockIdx>>3
    // (0..63) -> l-chunk of 64. 4 adjacent lanes share l (their 4 heads form
    // one contiguous 1 KB K chunk -> coalesced), 64 l per block.
    int xcd  = blockIdx.x & 7;
    int slot = blockIdx.x >> 3;
    int b  = xcd >> 1;
    int hh = xcd & 1;
    int t  = threadIdx.x;
    int h  = (hh << 2) | (t & 3);
    int l  = (slot << 6) | (t >> 2);

    const f32x4* qp = reinterpret_cast<const f32x4*>(
        Q + (((size_t)b * LSEQ + l) * NH + h) * ND);
    f32x4 q4[16];
    #pragma unroll
    for (int i = 0; i < 16; ++i) q4[i] = __builtin_nontemporal_load(qp + i);

    const int* is = idxS + (size_t)l * NSAMP;
    size_t kbh = ((size_t)b * LSEQ * NH + h) * ND;

    float maxv = -INFINITY;
    float sumv = 0.0f;

    auto loadK = [&](f32x4 (&dst)[16], int idx) {
        const f32x4* kp = reinterpret_cast<const f32x4*>(
            K + kbh + (size_t)idx * (NH * ND));
        #pragma unroll
        for (int i = 0; i < 16; ++i) dst[i] = kp[i];
    };

    // EXACT same arithmetic as prior rounds: stage off=32 fused with
    // products, then off=16,8,4,2,1; sequential maxv/sumv updates.
    auto step = [&](const f32x4 (&k4)[16]) {
        float w[32];
        #pragma unroll
        for (int i = 0; i < 8; ++i) {
            f32x4 a = q4[i], bb = k4[i], c = q4[i + 8], d4 = k4[i + 8];
            w[4 * i + 0] = __fadd_rn(__fmul_rn(a.x, bb.x), __fmul_rn(c.x, d4.x));
            w[4 * i + 1] = __fadd_rn(__fmul_rn(a.y, bb.y), __fmul_rn(c.y, d4.y));
            w[4 * i + 2] = __fadd_rn(__fmul_rn(a.z, bb.z), __fmul_rn(c.z, d4.z));
            w[4 * i + 3] = __fadd_rn(__fmul_rn(a.w, bb.w), __fmul_rn(c.w, d4.w));
        }
        #pragma unroll
        for (int off = 16; off; off >>= 1) {
            #pragma unroll
            for (int i = 0; i < off; ++i) w[i] = __fadd_rn(w[i], w[i + off]);
        }
        float p = w[0];
        maxv = fmaxf(maxv, p);
        sumv = __fadd_rn(sumv, p);
    };

    // Software pipeline: 2 samples per iteration, idx fetched one iteration
    // ahead, K rows double-buffered (ka/kb). Sample ORDER s=0..44 preserved.
    // sched_barrier(0) between load-issue and tree keeps 16 loads in flight
    // during every tree (forbids load sinking).
    f32x4 ka[16], kb[16];
    int j1 = is[1];
    int j2 = is[2];
    loadK(ka, is[0]);

    for (int s = 0; s < NSAMP - 1; s += 2) {
        int j3 = 0, j4 = 0;
        if (s + 3 < NSAMP) j3 = is[s + 3];
        if (s + 4 < NSAMP) j4 = is[s + 4];
        loadK(kb, j1);                        // K row for sample s+1 in flight
        __builtin_amdgcn_sched_barrier(0);
        step(ka);                             // sample s
        __builtin_amdgcn_sched_barrier(0);
        loadK(ka, j2);                        // K row for sample s+2 in flight
        __builtin_amdgcn_sched_barrier(0);
        step(kb);                             // sample s+1
        __builtin_amdgcn_sched_barrier(0);
        j1 = j3; j2 = j4;
    }
    step(ka);                                 // sample 44 (loaded at s=42)

    Mout[((size_t)b * NH + h) * LSEQ + l] = maxv - sumv * (1.0f / (float)LSEQ);
}

// ---------------------------------------------------------------------------
// Kernel 2: top-45 per (b,h). UNCHANGED (selection semantics frozen).
// ---------------------------------------------------------------------------
__global__ __launch_bounds__(256) void topk_kernel(
        const float* __restrict__ M, int* __restrict__ Mtop) {
    int bh = blockIdx.x;
    int t = threadIdx.x;
    int wave = t >> 6, lane = t & 63;
    const float* m = M + (size_t)bh * LSEQ;

    float rv[16];
    #pragma unroll
    for (int k = 0; k < 16; ++k) rv[k] = m[t + (k << 8)];

    __shared__ float wv[4];
    __shared__ int   wi[4];
    __shared__ int   winIdx;

    for (int iter = 0; iter < NTOP; ++iter) {
        float bv = -INFINITY; int bi = 0x7fffffff;
        #pragma unroll
        for (int k = 0; k < 16; ++k) {
            float v = rv[k];
            if (v > bv) { bv = v; bi = t + (k << 8); }
        }
        #pragma unroll
        for (int off = 1; off < 64; off <<= 1) {
            float ov = __shfl_xor(bv, off, 64);
            int   oi = __shfl_xor(bi, off, 64);
            if (ov > bv || (ov == bv && oi < bi)) { bv = ov; bi = oi; }
        }
        if (lane == 0) { wv[wave] = bv; wi[wave] = bi; }
        __syncthreads();
        if (t == 0) {
            float cv = wv[0]; int ci = wi[0];
            for (int ww = 1; ww < 4; ++ww) {
                if (wv[ww] > cv || (wv[ww] == cv && wi[ww] < ci)) { cv = wv[ww]; ci = wi[ww]; }
            }
            winIdx = ci;
            Mtop[bh * NTOP + iter] = ci;
        }
        __syncthreads();
        int widx = winIdx;
        #pragma unroll
        for (int k = 0; k < 16; ++k)
            if (widx == t + (k << 8)) rv[k] = -INFINITY;
        __syncthreads();
    }
}

// ---------------------------------------------------------------------------
// Kernel 3a: per-chunk sums of V (16 chunks of 256 rows per (b,h)).
// Grid 512 = (bh,c); 256 thr = 4 row-groups x 64 d. Reads 32 MB once.
// ---------------------------------------------------------------------------
__global__ __launch_bounds__(256) void cumsumA_kernel(
        const float* __restrict__ V, float* __restrict__ chunkSums) {
    int blk = blockIdx.x;
    int c = blk & 15;
    int bh = blk >> 4;
    int h = bh & (NH - 1);
    int b = bh >> 3;
    int g = threadIdx.x >> 6, d = threadIdx.x & 63;

    const size_t rstride = (size_t)NH * ND;   // 512
    size_t vbase = (size_t)b * LSEQ * rstride + (size_t)h * ND + d;

    int l0 = c * 256 + g * 64;
    float s = 0.0f;
    for (int l = l0; l < l0 + 64; ++l) s += V[vbase + (size_t)l * rstride];

    __shared__ float part[4][ND];
    part[g][d] = s;
    __syncthreads();
    if (threadIdx.x < ND)
        chunkSums[(size_t)blk * ND + d] =
            part[0][d] + part[1][d] + part[2][d] + part[3][d];
}

// ---------------------------------------------------------------------------
// Kernel 3b: rescan chunk with exclusive prefix from chunkSums, write out.
// Grid 512 = (bh,c); 256 thr = 4 row-groups x 64 d. Reads 32 MB + writes 32.
// ---------------------------------------------------------------------------
__global__ __launch_bounds__(256) void cumsumC_kernel(
        const float* __restrict__ V, const float* __restrict__ chunkSums,
        float* __restrict__ out) {
    int blk = blockIdx.x;
    int c = blk & 15;
    int bh = blk >> 4;
    int h = bh & (NH - 1);
    int b = bh >> 3;
    int g = threadIdx.x >> 6, d = threadIdx.x & 63;

    const size_t rstride = (size_t)NH * ND;
    size_t vbase = (size_t)b * LSEQ * rstride + (size_t)h * ND + d;

    // prefix over earlier chunks
    float run = 0.0f;
    for (int cc = 0; cc < c; ++cc)
        run += chunkSums[((size_t)bh * 16 + cc) * ND + d];

    // within-chunk group partials
    int l0 = c * 256 + g * 64;
    float s = 0.0f;
    for (int l = l0; l < l0 + 64; ++l) s += V[vbase + (size_t)l * rstride];
    __shared__ float part[4][ND];
    part[g][d] = s;
    __syncthreads();
    for (int gg = 0; gg < g; ++gg) run += part[gg][d];

    size_t obase = (size_t)bh * LSEQ * ND + d;
    for (int l = l0; l < l0 + 64; ++l) {
        run += V[vbase + (size_t)l * rstride];
        out[obase + (size_t)l * ND] = run;
    }
}

// ---------------------------------------------------------------------------
// Kernel 4: per (b,h,u) flash attention, LDS-tiled (body as round 6).
// blockIdx remapped so all 45 u-blocks of one (b,h) land on ONE XCD
// (round-robin heuristic) and share the K/V stream in that XCD's L2.
// ---------------------------------------------------------------------------
#define TJ 64
__global__ __launch_bounds__(256) void attn_rows_kernel(
        const float* __restrict__ Q,
        const float* __restrict__ K,
        const float* __restrict__ V,
        const int* __restrict__ Mtop,
        float* __restrict__ out) {
    int x = blockIdx.x;
    int xcd = x & 7;
    int slot = x >> 3;           // 0..179
    int grp = slot / NTOP;       // 0..3
    int u = slot % NTOP;
    int bh = grp * 8 + xcd;      // all u of this bh share an XCD
    int h = bh & (NH - 1);
    int b = bh >> 3;
    int pos = Mtop[bh * NTOP + u];
    int n = pos + 1;
    int t = threadIdx.x;
    int r = t >> 2, qt = t & 3;

    __shared__ float Ks[TJ][65];
    __shared__ float Vs[TJ][65];
    __shared__ float red[256];

    const size_t rstride = (size_t)NH * ND;   // 512
    size_t base = (size_t)b * LSEQ * rstride + (size_t)h * ND;

    float qreg[16];
    const float* qrow = Q + base + (size_t)pos * rstride + qt * 16;
    #pragma unroll
    for (int i = 0; i < 16; i += 4) {
        float4 v4 = *reinterpret_cast<const float4*>(qrow + i);
        qreg[i] = v4.x; qreg[i + 1] = v4.y; qreg[i + 2] = v4.z; qreg[i + 3] = v4.w;
    }

    float m = -INFINITY, s = 0.0f;
    float o[16];
    #pragma unroll
    for (int dd = 0; dd < 16; ++dd) o[dd] = 0.0f;

    int ntiles = (n + TJ - 1) / TJ;
    for (int tt = 0; tt < ntiles; ++tt) {
        int j0 = tt * TJ;
        __syncthreads();
        #pragma unroll
        for (int i = 0; i < 4; ++i) {
            int u16 = t + i * 256;
            int rr = u16 >> 4, cc = u16 & 15;
            int j = j0 + rr;
            int jc = (j < n) ? j : (n - 1);
            const float* rowk = K + base + (size_t)jc * rstride;
            float4 kv = *reinterpret_cast<const float4*>(rowk + cc * 4);
            Ks[rr][cc * 4 + 0] = kv.x; Ks[rr][cc * 4 + 1] = kv.y;
            Ks[rr][cc * 4 + 2] = kv.z; Ks[rr][cc * 4 + 3] = kv.w;
            const float* rowv = V + base + (size_t)jc * rstride;
            float4 vv = *reinterpret_cast<const float4*>(rowv + cc * 4);
            Vs[rr][cc * 4 + 0] = vv.x; Vs[rr][cc * 4 + 1] = vv.y;
            Vs[rr][cc * 4 + 2] = vv.z; Vs[rr][cc * 4 + 3] = vv.w;
        }
        __syncthreads();

        int j = j0 + r;
        float acc = 0.0f;
        #pragma unroll
        for (int dd = 0; dd < 16; ++dd)
            acc = fmaf(qreg[dd], Ks[r][qt * 16 + dd], acc);
        acc += __shfl_xor(acc, 1, 64);
        acc += __shfl_xor(acc, 2, 64);

        if (j < n) {
            float sc = acc * 0.125f;
            if (sc > m) {
                float alpha = __expf(m - sc);
                s *= alpha;
                #pragma unroll
                for (int dd = 0; dd < 16; ++dd) o[dd] *= alpha;
                m = sc;
            }
            float e = __expf(sc - m);
            s += e;
            #pragma unroll
            for (int dd = 0; dd < 16; ++dd)
                o[dd] = fmaf(e, Vs[r][qt * 16 + dd], o[dd]);
        }
    }
    __syncthreads();

    red[t] = m; __syncthreads();
    for (int sft = 128; sft; sft >>= 1) {
        if (t < sft) red[t] = fmaxf(red[t], red[t + sft]);
        __syncthreads();
    }
    float mstar = red[0]; __syncthreads();
    float a = __expf(m - mstar);

    red[t] = s * a; __syncthreads();
    for (int sft = 128; sft; sft >>= 1) {
        if (t < sft) red[t] += red[t + sft];
        __syncthreads();
    }
    float S = red[0]; __syncthreads();

    float* OB = &Ks[0][0];
    #pragma unroll
    for (int dd = 0; dd < 16; ++dd) OB[t * 16 + dd] = o[dd] * a;
    __syncthreads();

    if (t < ND) {
        int qtt = t >> 4, dd = t & 15;
        float tot = 0.0f;
        for (int k = 0; k < 64; ++k) tot += OB[(4 * k + qtt) * 16 + dd];
        out[((size_t)bh * LSEQ + pos) * ND + t] = tot / S;
    }
}

// ---------------------------------------------------------------------------
extern "C" void kernel_launch(void* const* d_in, const int* in_sizes, int n_in,
                              void* d_out, int out_size, void* d_ws, size_t ws_size,
                              hipStream_t stream) {
    const float* Q = (const float*)d_in[0];
    const float* K = (const float*)d_in[1];
    const float* V = (const float*)d_in[2];
    const int* idxS = (const int*)d_in[3];
    float* out = (float*)d_out;

    // M (fp32, 512 KB) lives in d_out — consumed by topk before cumsum
    // overwrites d_out. ws: Mtop (5760 B) @0, chunkSums (128 KB) @8192.
    float* Mbuf = (float*)d_out;
    int*   Mtop = (int*)d_ws;
    float* chunkSums = (float*)((char*)d_ws + 8192);

    compute_M_kernel<<<512, 256, 0, stream>>>(Q, K, idxS, Mbuf);
    topk_kernel<<<NB * NH, 256, 0, stream>>>(Mbuf, Mtop);
    cumsumA_kernel<<<NB * NH * 16, 256, 0, stream>>>(V, chunkSums);
    cumsumC_kernel<<<NB * NH * 16, 256, 0, stream>>>(V, chunkSums, out);
    attn_rows_kernel<<<NB * NH * NTOP, 256, 0, stream>>>(Q, K, V, Mtop, out);
}

// Round 5
// 500.179 us; speedup vs baseline: 1.3727x; 1.1289x over previous
//
#include <hip/hip_runtime.h>

// Problem constants (B, L, H, D) = (4, 4096, 8, 64), FACTOR=5
#define NB 4
#define LSEQ 4096
#define NH 8
#define ND 64
#define NSAMP 45
#define NTOP 45

typedef float f32x4 __attribute__((ext_vector_type(4)));

// ---------------------------------------------------------------------------
// Kernel 0 (prep): per l, bucket-sort the 45 (idx,s) pairs by 256-row chunk
// (chunk = idx>>8). idxS is SHARED across all (b,h) -> sort once, reuse 32x.
// Output pack = (idx<<8)|s, grouped by chunk, within-chunk in s-order.
// Dots are order-independent; the final maxv/sumv fold uses original s order
// -> M stays bit-identical regardless of computation order.
// ---------------------------------------------------------------------------
__global__ __launch_bounds__(256) void prep_kernel(
        const int* __restrict__ idxS, int* __restrict__ sortedPack) {
    int t = threadIdx.x;
    int l = blockIdx.x * 256 + t;
    const int* is = idxS + (size_t)l * NSAMP;
    __shared__ int cnt[256][17];            // +1 pad: bank-conflict-free
    #pragma unroll
    for (int c = 0; c < 16; ++c) cnt[t][c] = 0;
    for (int s = 0; s < NSAMP; ++s) cnt[t][is[s] >> 8] += 1;
    int run = 0;
    #pragma unroll
    for (int c = 0; c < 16; ++c) { int v = cnt[t][c]; cnt[t][c] = run; run += v; }
    for (int s = 0; s < NSAMP; ++s) {
        int idx = is[s];
        int pos = cnt[t][idx >> 8]++;
        sortedPack[(size_t)l * NSAMP + pos] = (idx << 8) | s;
    }
}

// ---------------------------------------------------------------------------
// Kernel 1: M[b,h,l] = max_s(q.k_s) - sum_s(q.k_s)/LSEQ.
// Round-10: LDS-staged gather. r4 post-mortem: 1.5 GB of random 64B L2
// gather caps at ~7.6 TB/s effective (L2 request-throughput wall) -> 198 us.
// Here K is STREAMED chunk-by-chunk (256 rows) into LDS once per block
// (sequential L2 reads), and the 45-sample gather runs against LDS.
// Block = (bh, 512 l's); thread owns l0=base+t and l1=base+256+t, q rows in
// regs. Per chunk: stage -> barrier -> per-l while-loop over the chunk's
// pre-sorted samples -> dot from LDS -> park in Plds[l][s] -> barrier.
// After all chunks: fold Plds in ORIGINAL s order with the EXACT original
// fmaxf/__fadd_rn sequence -> M bit-identical -> selection frozen.
// Ks padded to 68 floats/row: 16B-aligned b128 reads, row r window start
// 4(r+c)%32 -> 8 bank-window positions -> near-baseline LDS conflict cost.
// LDS: Ks 256*68*4=69632 + Plds 512*45*4=92160 = 161792 B (<160 KiB).
// ---------------------------------------------------------------------------
__global__ __launch_bounds__(256, 1) void compute_M_kernel(
        const float* __restrict__ Q,
        const float* __restrict__ K,
        const int* __restrict__ sortedPack,
        float* __restrict__ Mout) {
    int xcd = blockIdx.x & 7;              // XCD slot (round-robin dispatch)
    int sub = blockIdx.x >> 3;             // 0..31
    int bh  = (xcd << 2) | (sub & 3);      // 4 bh per XCD -> 4MB L2 K stream
    int lt  = sub >> 2;                    // 0..7 (512-l tile)
    int b = bh >> 3, h = bh & 7;
    int t = threadIdx.x;
    int l0 = (lt << 9) + t;
    int l1 = l0 + 256;

    __shared__ float Ks[256 * 68];
    __shared__ float Plds[512 * 45];

    // Q rows in regs (nontemporal: one-shot stream, keep L2 for K).
    f32x4 qa[16], qb[16];
    {
        const f32x4* qp0 = reinterpret_cast<const f32x4*>(
            Q + (((size_t)b * LSEQ + l0) * NH + h) * ND);
        const f32x4* qp1 = reinterpret_cast<const f32x4*>(
            Q + (((size_t)b * LSEQ + l1) * NH + h) * ND);
        #pragma unroll
        for (int i = 0; i < 16; ++i) qa[i] = __builtin_nontemporal_load(qp0 + i);
        #pragma unroll
        for (int i = 0; i < 16; ++i) qb[i] = __builtin_nontemporal_load(qp1 + i);
    }

    // EXACT original tree: products, off=32 fused, then 16/8/4/2/1.
    auto dotQK = [&](const f32x4 (&q4)[16], const float* kr) -> float {
        const f32x4* k4 = reinterpret_cast<const f32x4*>(kr);
        float w[32];
        #pragma unroll
        for (int i = 0; i < 8; ++i) {
            f32x4 a = q4[i], bb = k4[i], c = q4[i + 8], d4 = k4[i + 8];
            w[4 * i + 0] = __fadd_rn(__fmul_rn(a.x, bb.x), __fmul_rn(c.x, d4.x));
            w[4 * i + 1] = __fadd_rn(__fmul_rn(a.y, bb.y), __fmul_rn(c.y, d4.y));
            w[4 * i + 2] = __fadd_rn(__fmul_rn(a.z, bb.z), __fmul_rn(c.z, d4.z));
            w[4 * i + 3] = __fadd_rn(__fmul_rn(a.w, bb.w), __fmul_rn(c.w, d4.w));
        }
        #pragma unroll
        for (int off = 16; off; off >>= 1) {
            #pragma unroll
            for (int i = 0; i < off; ++i) w[i] = __fadd_rn(w[i], w[i + off]);
        }
        return w[0];
    };

    const int* sp0 = sortedPack + (size_t)l0 * NSAMP;
    const int* sp1 = sortedPack + (size_t)l1 * NSAMP;
    int ptr0 = 0, ptr1 = 0;
    int pk0 = sp0[0], pk1 = sp1[0];

    size_t kbh = ((size_t)b * LSEQ * NH + h) * ND;

    for (int c = 0; c < 16; ++c) {
        // stage rows [c*256, c*256+256) of this (b,h): coalesced stream.
        #pragma unroll
        for (int i = 0; i < 16; ++i) {
            int flat = i * 256 + t;
            int row = flat >> 4, col = flat & 15;
            f32x4 v = *reinterpret_cast<const f32x4*>(
                K + kbh + (size_t)(c * 256 + row) * (NH * ND) + col * 4);
            *reinterpret_cast<f32x4*>(&Ks[row * 68 + col * 4]) = v;
        }
        __syncthreads();

        // samples of l0 in chunk c (pack>>16 == idx>>8 == chunk)
        while ((pk0 >> 16) == c) {
            int r = (pk0 >> 8) & 255;
            int s = pk0 & 255;
            Plds[t * 45 + s] = dotQK(qa, &Ks[r * 68]);
            ++ptr0;
            pk0 = (ptr0 < NSAMP) ? sp0[ptr0] : 0x7fffffff;
        }
        // samples of l1 in chunk c
        while ((pk1 >> 16) == c) {
            int r = (pk1 >> 8) & 255;
            int s = pk1 & 255;
            Plds[(256 + t) * 45 + s] = dotQK(qb, &Ks[r * 68]);
            ++ptr1;
            pk1 = (ptr1 < NSAMP) ? sp1[ptr1] : 0x7fffffff;
        }
        __syncthreads();
    }

    // Fold in ORIGINAL s order (thread reads only its own Plds entries).
    {
        float maxv = -INFINITY, sumv = 0.0f;
        for (int s = 0; s < NSAMP; ++s) {
            float v = Plds[t * 45 + s];
            maxv = fmaxf(maxv, v);
            sumv = __fadd_rn(sumv, v);
        }
        Mout[(size_t)bh * LSEQ + l0] = maxv - sumv * (1.0f / (float)LSEQ);
    }
    {
        float maxv = -INFINITY, sumv = 0.0f;
        for (int s = 0; s < NSAMP; ++s) {
            float v = Plds[(256 + t) * 45 + s];
            maxv = fmaxf(maxv, v);
            sumv = __fadd_rn(sumv, v);
        }
        Mout[(size_t)bh * LSEQ + l1] = maxv - sumv * (1.0f / (float)LSEQ);
    }
}

// ---------------------------------------------------------------------------
// Kernel 2: top-45 per (b,h). UNCHANGED (selection semantics frozen).
// ---------------------------------------------------------------------------
__global__ __launch_bounds__(256) void topk_kernel(
        const float* __restrict__ M, int* __restrict__ Mtop) {
    int bh = blockIdx.x;
    int t = threadIdx.x;
    int wave = t >> 6, lane = t & 63;
    const float* m = M + (size_t)bh * LSEQ;

    float rv[16];
    #pragma unroll
    for (int k = 0; k < 16; ++k) rv[k] = m[t + (k << 8)];

    __shared__ float wv[4];
    __shared__ int   wi[4];
    __shared__ int   winIdx;

    for (int iter = 0; iter < NTOP; ++iter) {
        float bv = -INFINITY; int bi = 0x7fffffff;
        #pragma unroll
        for (int k = 0; k < 16; ++k) {
            float v = rv[k];
            if (v > bv) { bv = v; bi = t + (k << 8); }
        }
        #pragma unroll
        for (int off = 1; off < 64; off <<= 1) {
            float ov = __shfl_xor(bv, off, 64);
            int   oi = __shfl_xor(bi, off, 64);
            if (ov > bv || (ov == bv && oi < bi)) { bv = ov; bi = oi; }
        }
        if (lane == 0) { wv[wave] = bv; wi[wave] = bi; }
        __syncthreads();
        if (t == 0) {
            float cv = wv[0]; int ci = wi[0];
            for (int ww = 1; ww < 4; ++ww) {
                if (wv[ww] > cv || (wv[ww] == cv && wi[ww] < ci)) { cv = wv[ww]; ci = wi[ww]; }
            }
            winIdx = ci;
            Mtop[bh * NTOP + iter] = ci;
        }
        __syncthreads();
        int widx = winIdx;
        #pragma unroll
        for (int k = 0; k < 16; ++k)
            if (widx == t + (k << 8)) rv[k] = -INFINITY;
        __syncthreads();
    }
}

// ---------------------------------------------------------------------------
// Kernel 3a: per-chunk sums of V (16 chunks of 256 rows per (b,h)).
// ---------------------------------------------------------------------------
__global__ __launch_bounds__(256) void cumsumA_kernel(
        const float* __restrict__ V, float* __restrict__ chunkSums) {
    int blk = blockIdx.x;
    int c = blk & 15;
    int bh = blk >> 4;
    int h = bh & (NH - 1);
    int b = bh >> 3;
    int g = threadIdx.x >> 6, d = threadIdx.x & 63;

    const size_t rstride = (size_t)NH * ND;   // 512
    size_t vbase = (size_t)b * LSEQ * rstride + (size_t)h * ND + d;

    int l0 = c * 256 + g * 64;
    float s = 0.0f;
    for (int l = l0; l < l0 + 64; ++l) s += V[vbase + (size_t)l * rstride];

    __shared__ float part[4][ND];
    part[g][d] = s;
    __syncthreads();
    if (threadIdx.x < ND)
        chunkSums[(size_t)blk * ND + d] =
            part[0][d] + part[1][d] + part[2][d] + part[3][d];
}

// ---------------------------------------------------------------------------
// Kernel 3b: rescan chunk with exclusive prefix from chunkSums, write out.
// ---------------------------------------------------------------------------
__global__ __launch_bounds__(256) void cumsumC_kernel(
        const float* __restrict__ V, const float* __restrict__ chunkSums,
        float* __restrict__ out) {
    int blk = blockIdx.x;
    int c = blk & 15;
    int bh = blk >> 4;
    int h = bh & (NH - 1);
    int b = bh >> 3;
    int g = threadIdx.x >> 6, d = threadIdx.x & 63;

    const size_t rstride = (size_t)NH * ND;
    size_t vbase = (size_t)b * LSEQ * rstride + (size_t)h * ND + d;

    float run = 0.0f;
    for (int cc = 0; cc < c; ++cc)
        run += chunkSums[((size_t)bh * 16 + cc) * ND + d];

    int l0 = c * 256 + g * 64;
    float s = 0.0f;
    for (int l = l0; l < l0 + 64; ++l) s += V[vbase + (size_t)l * rstride];
    __shared__ float part[4][ND];
    part[g][d] = s;
    __syncthreads();
    for (int gg = 0; gg < g; ++gg) run += part[gg][d];

    size_t obase = (size_t)bh * LSEQ * ND + d;
    for (int l = l0; l < l0 + 64; ++l) {
        run += V[vbase + (size_t)l * rstride];
        out[obase + (size_t)l * ND] = run;
    }
}

// ---------------------------------------------------------------------------
// Kernel 4: per (b,h,u) flash attention, LDS-tiled (body as round 6).
// ---------------------------------------------------------------------------
#define TJ 64
__global__ __launch_bounds__(256) void attn_rows_kernel(
        const float* __restrict__ Q,
        const float* __restrict__ K,
        const float* __restrict__ V,
        const int* __restrict__ Mtop,
        float* __restrict__ out) {
    int x = blockIdx.x;
    int xcd = x & 7;
    int slot = x >> 3;           // 0..179
    int grp = slot / NTOP;       // 0..3
    int u = slot % NTOP;
    int bh = grp * 8 + xcd;      // all u of this bh share an XCD
    int h = bh & (NH - 1);
    int b = bh >> 3;
    int pos = Mtop[bh * NTOP + u];
    int n = pos + 1;
    int t = threadIdx.x;
    int r = t >> 2, qt = t & 3;

    __shared__ float Ks[TJ][65];
    __shared__ float Vs[TJ][65];
    __shared__ float red[256];

    const size_t rstride = (size_t)NH * ND;   // 512
    size_t base = (size_t)b * LSEQ * rstride + (size_t)h * ND;

    float qreg[16];
    const float* qrow = Q + base + (size_t)pos * rstride + qt * 16;
    #pragma unroll
    for (int i = 0; i < 16; i += 4) {
        float4 v4 = *reinterpret_cast<const float4*>(qrow + i);
        qreg[i] = v4.x; qreg[i + 1] = v4.y; qreg[i + 2] = v4.z; qreg[i + 3] = v4.w;
    }

    float m = -INFINITY, s = 0.0f;
    float o[16];
    #pragma unroll
    for (int dd = 0; dd < 16; ++dd) o[dd] = 0.0f;

    int ntiles = (n + TJ - 1) / TJ;
    for (int tt = 0; tt < ntiles; ++tt) {
        int j0 = tt * TJ;
        __syncthreads();
        #pragma unroll
        for (int i = 0; i < 4; ++i) {
            int u16 = t + i * 256;
            int rr = u16 >> 4, cc = u16 & 15;
            int j = j0 + rr;
            int jc = (j < n) ? j : (n - 1);
            const float* rowk = K + base + (size_t)jc * rstride;
            float4 kv = *reinterpret_cast<const float4*>(rowk + cc * 4);
            Ks[rr][cc * 4 + 0] = kv.x; Ks[rr][cc * 4 + 1] = kv.y;
            Ks[rr][cc * 4 + 2] = kv.z; Ks[rr][cc * 4 + 3] = kv.w;
            const float* rowv = V + base + (size_t)jc * rstride;
            float4 vv = *reinterpret_cast<const float4*>(rowv + cc * 4);
            Vs[rr][cc * 4 + 0] = vv.x; Vs[rr][cc * 4 + 1] = vv.y;
            Vs[rr][cc * 4 + 2] = vv.z; Vs[rr][cc * 4 + 3] = vv.w;
        }
        __syncthreads();

        int j = j0 + r;
        float acc = 0.0f;
        #pragma unroll
        for (int dd = 0; dd < 16; ++dd)
            acc = fmaf(qreg[dd], Ks[r][qt * 16 + dd], acc);
        acc += __shfl_xor(acc, 1, 64);
        acc += __shfl_xor(acc, 2, 64);

        if (j < n) {
            float sc = acc * 0.125f;
            if (sc > m) {
                float alpha = __expf(m - sc);
                s *= alpha;
                #pragma unroll
                for (int dd = 0; dd < 16; ++dd) o[dd] *= alpha;
                m = sc;
            }
            float e = __expf(sc - m);
            s += e;
            #pragma unroll
            for (int dd = 0; dd < 16; ++dd)
                o[dd] = fmaf(e, Vs[r][qt * 16 + dd], o[dd]);
        }
    }
    __syncthreads();

    red[t] = m; __syncthreads();
    for (int sft = 128; sft; sft >>= 1) {
        if (t < sft) red[t] = fmaxf(red[t], red[t + sft]);
        __syncthreads();
    }
    float mstar = red[0]; __syncthreads();
    float a = __expf(m - mstar);

    red[t] = s * a; __syncthreads();
    for (int sft = 128; sft; sft >>= 1) {
        if (t < sft) red[t] += red[t + sft];
        __syncthreads();
    }
    float S = red[0]; __syncthreads();

    float* OB = &Ks[0][0];
    #pragma unroll
    for (int dd = 0; dd < 16; ++dd) OB[t * 16 + dd] = o[dd] * a;
    __syncthreads();

    if (t < ND) {
        int qtt = t >> 4, dd = t & 15;
        float tot = 0.0f;
        for (int k = 0; k < 64; ++k) tot += OB[(4 * k + qtt) * 16 + dd];
        out[((size_t)bh * LSEQ + pos) * ND + t] = tot / S;
    }
}

// ---------------------------------------------------------------------------
extern "C" void kernel_launch(void* const* d_in, const int* in_sizes, int n_in,
                              void* d_out, int out_size, void* d_ws, size_t ws_size,
                              hipStream_t stream) {
    const float* Q = (const float*)d_in[0];
    const float* K = (const float*)d_in[1];
    const float* V = (const float*)d_in[2];
    const int* idxS = (const int*)d_in[3];
    float* out = (float*)d_out;

    // d_out scratch layout (before cumsum overwrites it):
    //   M      @ 0       (512 KB) — consumed by topk
    //   sorted @ 1 MB    (737 KB) — consumed by compute_M
    // ws: Mtop (5760 B) @0, chunkSums (128 KB) @8192.
    float* Mbuf = (float*)d_out;
    int*   sortedPack = (int*)((char*)d_out + (1 << 20));
    int*   Mtop = (int*)d_ws;
    float* chunkSums = (float*)((char*)d_ws + 8192);

    prep_kernel<<<LSEQ / 256, 256, 0, stream>>>(idxS, sortedPack);
    compute_M_kernel<<<256, 256, 0, stream>>>(Q, K, sortedPack, Mbuf);
    topk_kernel<<<NB * NH, 256, 0, stream>>>(Mbuf, Mtop);
    cumsumA_kernel<<<NB * NH * 16, 256, 0, stream>>>(V, chunkSums);
    cumsumC_kernel<<<NB * NH * 16, 256, 0, stream>>>(V, chunkSums, out);
    attn_rows_kernel<<<NB * NH * NTOP, 256, 0, stream>>>(Q, K, V, Mtop, out);
}

// Round 6
// 436.647 us; speedup vs baseline: 1.5724x; 1.1455x over previous
//
#include <hip/hip_runtime.h>

// Problem constants (B, L, H, D) = (4, 4096, 8, 64), FACTOR=5
#define NB 4
#define LSEQ 4096
#define NH 8
#define ND 64
#define NSAMP 45
#define NTOP 45
#define ACH 256            // keys per attention chunk
#define NCH (LSEQ / ACH)   // 16 chunks

typedef float f32x4 __attribute__((ext_vector_type(4)));

// ---------------------------------------------------------------------------
// Kernel 0 (prep): per l, bucket-sort the 45 (idx,s) pairs by 256-row chunk.
// UNCHANGED (r10).
// ---------------------------------------------------------------------------
__global__ __launch_bounds__(256) void prep_kernel(
        const int* __restrict__ idxS, int* __restrict__ sortedPack) {
    int t = threadIdx.x;
    int l = blockIdx.x * 256 + t;
    const int* is = idxS + (size_t)l * NSAMP;
    __shared__ int cnt[256][17];
    #pragma unroll
    for (int c = 0; c < 16; ++c) cnt[t][c] = 0;
    for (int s = 0; s < NSAMP; ++s) cnt[t][is[s] >> 8] += 1;
    int run = 0;
    #pragma unroll
    for (int c = 0; c < 16; ++c) { int v = cnt[t][c]; cnt[t][c] = run; run += v; }
    for (int s = 0; s < NSAMP; ++s) {
        int idx = is[s];
        int pos = cnt[t][idx >> 8]++;
        sortedPack[(size_t)l * NSAMP + pos] = (idx << 8) | s;
    }
}

// ---------------------------------------------------------------------------
// Kernel 1: M[b,h,l]. LDS-staged gather (r10). UNCHANGED (selection frozen).
// ---------------------------------------------------------------------------
__global__ __launch_bounds__(256, 1) void compute_M_kernel(
        const float* __restrict__ Q,
        const float* __restrict__ K,
        const int* __restrict__ sortedPack,
        float* __restrict__ Mout) {
    int xcd = blockIdx.x & 7;
    int sub = blockIdx.x >> 3;
    int bh  = (xcd << 2) | (sub & 3);
    int lt  = sub >> 2;
    int b = bh >> 3, h = bh & 7;
    int t = threadIdx.x;
    int l0 = (lt << 9) + t;
    int l1 = l0 + 256;

    __shared__ float Ks[256 * 68];
    __shared__ float Plds[512 * 45];

    f32x4 qa[16], qb[16];
    {
        const f32x4* qp0 = reinterpret_cast<const f32x4*>(
            Q + (((size_t)b * LSEQ + l0) * NH + h) * ND);
        const f32x4* qp1 = reinterpret_cast<const f32x4*>(
            Q + (((size_t)b * LSEQ + l1) * NH + h) * ND);
        #pragma unroll
        for (int i = 0; i < 16; ++i) qa[i] = __builtin_nontemporal_load(qp0 + i);
        #pragma unroll
        for (int i = 0; i < 16; ++i) qb[i] = __builtin_nontemporal_load(qp1 + i);
    }

    auto dotQK = [&](const f32x4 (&q4)[16], const float* kr) -> float {
        const f32x4* k4 = reinterpret_cast<const f32x4*>(kr);
        float w[32];
        #pragma unroll
        for (int i = 0; i < 8; ++i) {
            f32x4 a = q4[i], bb = k4[i], c = q4[i + 8], d4 = k4[i + 8];
            w[4 * i + 0] = __fadd_rn(__fmul_rn(a.x, bb.x), __fmul_rn(c.x, d4.x));
            w[4 * i + 1] = __fadd_rn(__fmul_rn(a.y, bb.y), __fmul_rn(c.y, d4.y));
            w[4 * i + 2] = __fadd_rn(__fmul_rn(a.z, bb.z), __fmul_rn(c.z, d4.z));
            w[4 * i + 3] = __fadd_rn(__fmul_rn(a.w, bb.w), __fmul_rn(c.w, d4.w));
        }
        #pragma unroll
        for (int off = 16; off; off >>= 1) {
            #pragma unroll
            for (int i = 0; i < off; ++i) w[i] = __fadd_rn(w[i], w[i + off]);
        }
        return w[0];
    };

    const int* sp0 = sortedPack + (size_t)l0 * NSAMP;
    const int* sp1 = sortedPack + (size_t)l1 * NSAMP;
    int ptr0 = 0, ptr1 = 0;
    int pk0 = sp0[0], pk1 = sp1[0];

    size_t kbh = ((size_t)b * LSEQ * NH + h) * ND;

    for (int c = 0; c < 16; ++c) {
        #pragma unroll
        for (int i = 0; i < 16; ++i) {
            int flat = i * 256 + t;
            int row = flat >> 4, col = flat & 15;
            f32x4 v = *reinterpret_cast<const f32x4*>(
                K + kbh + (size_t)(c * 256 + row) * (NH * ND) + col * 4);
            *reinterpret_cast<f32x4*>(&Ks[row * 68 + col * 4]) = v;
        }
        __syncthreads();

        while ((pk0 >> 16) == c) {
            int r = (pk0 >> 8) & 255;
            int s = pk0 & 255;
            Plds[t * 45 + s] = dotQK(qa, &Ks[r * 68]);
            ++ptr0;
            pk0 = (ptr0 < NSAMP) ? sp0[ptr0] : 0x7fffffff;
        }
        while ((pk1 >> 16) == c) {
            int r = (pk1 >> 8) & 255;
            int s = pk1 & 255;
            Plds[(256 + t) * 45 + s] = dotQK(qb, &Ks[r * 68]);
            ++ptr1;
            pk1 = (ptr1 < NSAMP) ? sp1[ptr1] : 0x7fffffff;
        }
        __syncthreads();
    }

    {
        float maxv = -INFINITY, sumv = 0.0f;
        for (int s = 0; s < NSAMP; ++s) {
            float v = Plds[t * 45 + s];
            maxv = fmaxf(maxv, v);
            sumv = __fadd_rn(sumv, v);
        }
        Mout[(size_t)bh * LSEQ + l0] = maxv - sumv * (1.0f / (float)LSEQ);
    }
    {
        float maxv = -INFINITY, sumv = 0.0f;
        for (int s = 0; s < NSAMP; ++s) {
            float v = Plds[(256 + t) * 45 + s];
            maxv = fmaxf(maxv, v);
            sumv = __fadd_rn(sumv, v);
        }
        Mout[(size_t)bh * LSEQ + l1] = maxv - sumv * (1.0f / (float)LSEQ);
    }
}

// ---------------------------------------------------------------------------
// Kernel 2: top-45 per (b,h). UNCHANGED (selection semantics frozen).
// ---------------------------------------------------------------------------
__global__ __launch_bounds__(256) void topk_kernel(
        const float* __restrict__ M, int* __restrict__ Mtop) {
    int bh = blockIdx.x;
    int t = threadIdx.x;
    int wave = t >> 6, lane = t & 63;
    const float* m = M + (size_t)bh * LSEQ;

    float rv[16];
    #pragma unroll
    for (int k = 0; k < 16; ++k) rv[k] = m[t + (k << 8)];

    __shared__ float wv[4];
    __shared__ int   wi[4];
    __shared__ int   winIdx;

    for (int iter = 0; iter < NTOP; ++iter) {
        float bv = -INFINITY; int bi = 0x7fffffff;
        #pragma unroll
        for (int k = 0; k < 16; ++k) {
            float v = rv[k];
            if (v > bv) { bv = v; bi = t + (k << 8); }
        }
        #pragma unroll
        for (int off = 1; off < 64; off <<= 1) {
            float ov = __shfl_xor(bv, off, 64);
            int   oi = __shfl_xor(bi, off, 64);
            if (ov > bv || (ov == bv && oi < bi)) { bv = ov; bi = oi; }
        }
        if (lane == 0) { wv[wave] = bv; wi[wave] = bi; }
        __syncthreads();
        if (t == 0) {
            float cv = wv[0]; int ci = wi[0];
            for (int ww = 1; ww < 4; ++ww) {
                if (wv[ww] > cv || (wv[ww] == cv && wi[ww] < ci)) { cv = wv[ww]; ci = wi[ww]; }
            }
            winIdx = ci;
            Mtop[bh * NTOP + iter] = ci;
        }
        __syncthreads();
        int widx = winIdx;
        #pragma unroll
        for (int k = 0; k < 16; ++k)
            if (widx == t + (k << 8)) rv[k] = -INFINITY;
        __syncthreads();
    }
}

// ---------------------------------------------------------------------------
// Kernel 3a/3b: V cumsum. UNCHANGED.
// ---------------------------------------------------------------------------
__global__ __launch_bounds__(256) void cumsumA_kernel(
        const float* __restrict__ V, float* __restrict__ chunkSums) {
    int blk = blockIdx.x;
    int c = blk & 15;
    int bh = blk >> 4;
    int h = bh & (NH - 1);
    int b = bh >> 3;
    int g = threadIdx.x >> 6, d = threadIdx.x & 63;

    const size_t rstride = (size_t)NH * ND;
    size_t vbase = (size_t)b * LSEQ * rstride + (size_t)h * ND + d;

    int l0 = c * 256 + g * 64;
    float s = 0.0f;
    for (int l = l0; l < l0 + 64; ++l) s += V[vbase + (size_t)l * rstride];

    __shared__ float part[4][ND];
    part[g][d] = s;
    __syncthreads();
    if (threadIdx.x < ND)
        chunkSums[(size_t)blk * ND + d] =
            part[0][d] + part[1][d] + part[2][d] + part[3][d];
}

__global__ __launch_bounds__(256) void cumsumC_kernel(
        const float* __restrict__ V, const float* __restrict__ chunkSums,
        float* __restrict__ out) {
    int blk = blockIdx.x;
    int c = blk & 15;
    int bh = blk >> 4;
    int h = bh & (NH - 1);
    int b = bh >> 3;
    int g = threadIdx.x >> 6, d = threadIdx.x & 63;

    const size_t rstride = (size_t)NH * ND;
    size_t vbase = (size_t)b * LSEQ * rstride + (size_t)h * ND + d;

    float run = 0.0f;
    for (int cc = 0; cc < c; ++cc)
        run += chunkSums[((size_t)bh * 16 + cc) * ND + d];

    int l0 = c * 256 + g * 64;
    float s = 0.0f;
    for (int l = l0; l < l0 + 64; ++l) s += V[vbase + (size_t)l * rstride];
    __shared__ float part[4][ND];
    part[g][d] = s;
    __syncthreads();
    for (int gg = 0; gg < g; ++gg) run += part[gg][d];

    size_t obase = (size_t)bh * LSEQ * ND + d;
    for (int l = l0; l < l0 + 64; ++l) {
        run += V[vbase + (size_t)l * rstride];
        out[obase + (size_t)l * ND] = run;
    }
}

// ---------------------------------------------------------------------------
// Kernel 4 (NEW): flash split-K attention sharing the K/V stream across all
// 45 queries of a bh. Grid = (bh, 16 chunks of 256 keys); block 256 = 4
// waves. Per 64-key tile: V staged once in LDS (row-major [64][68], b128
// aligned), K tile in REGISTERS (lane=key, 16 f32x4), then wave w serves
// queries u = w,w+4,... (<=12) with per-query state {f32x4 o, m, s}:
//   phase A keys-in-lanes: 64 fmaf dot (Q broadcast from LDS) -> score ->
//     wave max/sum via shfl -> P through per-wave LDS row;
//   phase B dims x keys: lane (jj,dq) accumulates o[4dq..] over keys 4i+jj.
// Writes per-(query,chunk) partials {m,s,o[64]} (stride 72) to d_out scratch.
// vs r6 attn_rows: K/V staged ONCE per chunk instead of 45x -> 45x less
// LDS/L2 staging traffic; no per-query barriers.
// ---------------------------------------------------------------------------
__global__ __launch_bounds__(256, 1) void attn_partial_kernel(
        const float* __restrict__ Q, const float* __restrict__ K,
        const float* __restrict__ V, const int* __restrict__ Mtop,
        float* __restrict__ part) {
    int bh = blockIdx.x >> 4;
    int c  = blockIdx.x & 15;
    int b = bh >> 3, h = bh & 7;
    int t = threadIdx.x;
    int w = t >> 6, lane = t & 63;
    int jj = lane >> 4, dq = lane & 15;

    __shared__ float Qs[NTOP * ND];
    __shared__ int   posS[NTOP];
    __shared__ float Vs[64][68];
    __shared__ float Pw[4][64];

    size_t base = ((size_t)b * LSEQ * NH + h) * ND;

    if (t < NTOP) posS[t] = Mtop[bh * NTOP + t];
    __syncthreads();
    for (int idx = t; idx < NTOP * 16; idx += 256) {
        int u = idx >> 4, cg = idx & 15;
        f32x4 v = *reinterpret_cast<const f32x4*>(
            Q + base + (size_t)posS[u] * (NH * ND) + cg * 4);
        *reinterpret_cast<f32x4*>(&Qs[u * ND + cg * 4]) = v;
    }

    f32x4 o[12];
    float mreg[12], sreg[12];
    #pragma unroll
    for (int qi = 0; qi < 12; ++qi) {
        o[qi] = 0.0f; mreg[qi] = -INFINITY; sreg[qi] = 0.0f;
    }

    for (int tt = 0; tt < ACH / 64; ++tt) {
        int tile0 = c * ACH + tt * 64;
        __syncthreads();
        #pragma unroll
        for (int i = 0; i < 4; ++i) {
            int flat = i * 256 + t;
            int r = flat >> 4, cg = flat & 15;
            f32x4 v = *reinterpret_cast<const f32x4*>(
                V + base + (size_t)(tile0 + r) * (NH * ND) + cg * 4);
            *reinterpret_cast<f32x4*>(&Vs[r][cg * 4]) = v;
        }
        __syncthreads();

        f32x4 kreg[16];
        #pragma unroll
        for (int i = 0; i < 16; ++i)
            kreg[i] = *reinterpret_cast<const f32x4*>(
                K + base + (size_t)(tile0 + lane) * (NH * ND) + i * 4);

        #pragma unroll
        for (int qi = 0; qi < 12; ++qi) {
            int u = w + 4 * qi;
            if (u >= NTOP) continue;
            int pu = posS[u];
            if (pu < tile0) continue;

            float a0 = 0, a1 = 0, a2 = 0, a3 = 0;
            #pragma unroll
            for (int di = 0; di < 16; ++di) {
                f32x4 qv = *reinterpret_cast<const f32x4*>(&Qs[u * ND + di * 4]);
                a0 = fmaf(qv.x, kreg[di].x, a0);
                a1 = fmaf(qv.y, kreg[di].y, a1);
                a2 = fmaf(qv.z, kreg[di].z, a2);
                a3 = fmaf(qv.w, kreg[di].w, a3);
            }
            float sc = ((a0 + a1) + (a2 + a3)) * 0.125f;
            if (tile0 + lane > pu) sc = -INFINITY;

            float tmax = sc;
            #pragma unroll
            for (int off = 1; off < 64; off <<= 1)
                tmax = fmaxf(tmax, __shfl_xor(tmax, off, 64));
            float mold = mreg[qi];
            float mnew = fmaxf(mold, tmax);
            float alpha = __expf(mold - mnew);   // mold=-inf -> 0
            float e = __expf(sc - mnew);          // masked -> 0
            float esum = e;
            #pragma unroll
            for (int off = 1; off < 64; off <<= 1)
                esum += __shfl_xor(esum, off, 64);
            sreg[qi] = sreg[qi] * alpha + esum;
            mreg[qi] = mnew;
            Pw[w][lane] = e;
            o[qi] *= alpha;
            #pragma unroll
            for (int i = 0; i < 16; ++i) {
                float pe = Pw[w][i * 4 + jj];
                f32x4 vv = *reinterpret_cast<const f32x4*>(&Vs[i * 4 + jj][dq * 4]);
                o[qi] += vv * pe;
            }
        }
    }

    // write partials (active queries only): reduce o across jj groups.
    #pragma unroll
    for (int qi = 0; qi < 12; ++qi) {
        int u = w + 4 * qi;
        if (u >= NTOP) continue;
        if (posS[u] < c * ACH) continue;
        f32x4 oo = o[qi];
        #pragma unroll
        for (int off = 16; off <= 32; off <<= 1) {
            oo.x += __shfl_xor(oo.x, off, 64);
            oo.y += __shfl_xor(oo.y, off, 64);
            oo.z += __shfl_xor(oo.z, off, 64);
            oo.w += __shfl_xor(oo.w, off, 64);
        }
        size_t pb = ((size_t)(bh * NTOP + u) * NCH + c) * 72;
        if (lane < 16)
            *reinterpret_cast<f32x4*>(&part[pb + 4 + dq * 4]) = oo;
        if (lane == 0) { part[pb] = mreg[qi]; part[pb + 1] = sreg[qi]; }
    }
}

// ---------------------------------------------------------------------------
// Kernel 5 (NEW): merge chunk partials -> compact ctx[bh*45+u][64] (in ws).
// Runs BEFORE cumsum overwrites d_out (partials live in d_out scratch).
// ---------------------------------------------------------------------------
__global__ __launch_bounds__(256) void attn_merge_kernel(
        const float* __restrict__ part, const int* __restrict__ Mtop,
        float* __restrict__ ctx) {
    int j = blockIdx.x * 4 + (threadIdx.x >> 6);
    int lane = threadIdx.x & 63;
    int bh = j / NTOP, u = j - bh * NTOP;
    int pos = Mtop[bh * NTOP + u];
    int cmax = pos >> 8;                 // chunks 0..cmax are active
    size_t pb0 = (size_t)(bh * NTOP + u) * NCH * 72;
    float m = -INFINITY;
    for (int cc = 0; cc <= cmax; ++cc)
        m = fmaxf(m, part[pb0 + (size_t)cc * 72]);
    float S = 0.0f, oacc = 0.0f;
    for (int cc = 0; cc <= cmax; ++cc) {
        float mc = part[pb0 + (size_t)cc * 72];
        float sc = part[pb0 + (size_t)cc * 72 + 1];
        float wgt = __expf(mc - m);
        S = fmaf(sc, wgt, S);
        oacc = fmaf(part[pb0 + (size_t)cc * 72 + 4 + lane], wgt, oacc);
    }
    ctx[(size_t)j * ND + lane] = oacc / S;
}

// ---------------------------------------------------------------------------
// Kernel 6 (NEW): scatter ctx rows into out AFTER cumsum.
// ---------------------------------------------------------------------------
__global__ __launch_bounds__(256) void scatter_kernel(
        const float* __restrict__ ctx, const int* __restrict__ Mtop,
        float* __restrict__ out) {
    int j = blockIdx.x * 4 + (threadIdx.x >> 6);
    int lane = threadIdx.x & 63;
    int bh = j / NTOP, u = j - bh * NTOP;
    int pos = Mtop[bh * NTOP + u];
    out[((size_t)bh * LSEQ + pos) * ND + lane] = ctx[(size_t)j * ND + lane];
}

// ---------------------------------------------------------------------------
// Kernel 4-FALLBACK: old per-(bh,u) flash attention (r6). Used only if
// ws_size is too small for the compact ctx buffer.
// ---------------------------------------------------------------------------
#define TJ 64
__global__ __launch_bounds__(256) void attn_rows_kernel(
        const float* __restrict__ Q,
        const float* __restrict__ K,
        const float* __restrict__ V,
        const int* __restrict__ Mtop,
        float* __restrict__ out) {
    int x = blockIdx.x;
    int xcd = x & 7;
    int slot = x >> 3;
    int grp = slot / NTOP;
    int u = slot % NTOP;
    int bh = grp * 8 + xcd;
    int h = bh & (NH - 1);
    int b = bh >> 3;
    int pos = Mtop[bh * NTOP + u];
    int n = pos + 1;
    int t = threadIdx.x;
    int r = t >> 2, qt = t & 3;

    __shared__ float Ks[TJ][65];
    __shared__ float Vs[TJ][65];
    __shared__ float red[256];

    const size_t rstride = (size_t)NH * ND;
    size_t base = (size_t)b * LSEQ * rstride + (size_t)h * ND;

    float qreg[16];
    const float* qrow = Q + base + (size_t)pos * rstride + qt * 16;
    #pragma unroll
    for (int i = 0; i < 16; i += 4) {
        float4 v4 = *reinterpret_cast<const float4*>(qrow + i);
        qreg[i] = v4.x; qreg[i + 1] = v4.y; qreg[i + 2] = v4.z; qreg[i + 3] = v4.w;
    }

    float m = -INFINITY, s = 0.0f;
    float o[16];
    #pragma unroll
    for (int dd = 0; dd < 16; ++dd) o[dd] = 0.0f;

    int ntiles = (n + TJ - 1) / TJ;
    for (int tt = 0; tt < ntiles; ++tt) {
        int j0 = tt * TJ;
        __syncthreads();
        #pragma unroll
        for (int i = 0; i < 4; ++i) {
            int u16 = t + i * 256;
            int rr = u16 >> 4, cc = u16 & 15;
            int j = j0 + rr;
            int jc = (j < n) ? j : (n - 1);
            const float* rowk = K + base + (size_t)jc * rstride;
            float4 kv = *reinterpret_cast<const float4*>(rowk + cc * 4);
            Ks[rr][cc * 4 + 0] = kv.x; Ks[rr][cc * 4 + 1] = kv.y;
            Ks[rr][cc * 4 + 2] = kv.z; Ks[rr][cc * 4 + 3] = kv.w;
            const float* rowv = V + base + (size_t)jc * rstride;
            float4 vv = *reinterpret_cast<const float4*>(rowv + cc * 4);
            Vs[rr][cc * 4 + 0] = vv.x; Vs[rr][cc * 4 + 1] = vv.y;
            Vs[rr][cc * 4 + 2] = vv.z; Vs[rr][cc * 4 + 3] = vv.w;
        }
        __syncthreads();

        int j = j0 + r;
        float acc = 0.0f;
        #pragma unroll
        for (int dd = 0; dd < 16; ++dd)
            acc = fmaf(qreg[dd], Ks[r][qt * 16 + dd], acc);
        acc += __shfl_xor(acc, 1, 64);
        acc += __shfl_xor(acc, 2, 64);

        if (j < n) {
            float sc = acc * 0.125f;
            if (sc > m) {
                float alpha = __expf(m - sc);
                s *= alpha;
                #pragma unroll
                for (int dd = 0; dd < 16; ++dd) o[dd] *= alpha;
                m = sc;
            }
            float e = __expf(sc - m);
            s += e;
            #pragma unroll
            for (int dd = 0; dd < 16; ++dd)
                o[dd] = fmaf(e, Vs[r][qt * 16 + dd], o[dd]);
        }
    }
    __syncthreads();

    red[t] = m; __syncthreads();
    for (int sft = 128; sft; sft >>= 1) {
        if (t < sft) red[t] = fmaxf(red[t], red[t + sft]);
        __syncthreads();
    }
    float mstar = red[0]; __syncthreads();
    float a = __expf(m - mstar);

    red[t] = s * a; __syncthreads();
    for (int sft = 128; sft; sft >>= 1) {
        if (t < sft) red[t] += red[t + sft];
        __syncthreads();
    }
    float S = red[0]; __syncthreads();

    float* OB = &Ks[0][0];
    #pragma unroll
    for (int dd = 0; dd < 16; ++dd) OB[t * 16 + dd] = o[dd] * a;
    __syncthreads();

    if (t < ND) {
        int qtt = t >> 4, dd = t & 15;
        float tot = 0.0f;
        for (int k = 0; k < 64; ++k) tot += OB[(4 * k + qtt) * 16 + dd];
        out[((size_t)bh * LSEQ + pos) * ND + t] = tot / S;
    }
}

// ---------------------------------------------------------------------------
extern "C" void kernel_launch(void* const* d_in, const int* in_sizes, int n_in,
                              void* d_out, int out_size, void* d_ws, size_t ws_size,
                              hipStream_t stream) {
    const float* Q = (const float*)d_in[0];
    const float* K = (const float*)d_in[1];
    const float* V = (const float*)d_in[2];
    const int* idxS = (const int*)d_in[3];
    float* out = (float*)d_out;

    // d_out scratch (all consumed before cumsum overwrites):
    //   M       @ 0     (512 KB)  -> topk
    //   sorted  @ 1 MB  (737 KB)  -> compute_M
    //   part    @ 2 MB  (6.6 MB)  -> attn_merge
    // ws: Mtop (5760B) @0, chunkSums (128KB) @8192, ctx (360KB) @139264.
    float* Mbuf = (float*)d_out;
    int*   sortedPack = (int*)((char*)d_out + (1 << 20));
    float* part = (float*)((char*)d_out + (2 << 20));
    int*   Mtop = (int*)d_ws;
    float* chunkSums = (float*)((char*)d_ws + 8192);
    float* ctx = (float*)((char*)d_ws + 8192 + 131072);
    size_t wsNeeded = 8192 + 131072 + (size_t)NB * NH * NTOP * ND * 4;

    prep_kernel<<<LSEQ / 256, 256, 0, stream>>>(idxS, sortedPack);
    compute_M_kernel<<<256, 256, 0, stream>>>(Q, K, sortedPack, Mbuf);
    topk_kernel<<<NB * NH, 256, 0, stream>>>(Mbuf, Mtop);

    if (ws_size >= wsNeeded) {
        attn_partial_kernel<<<NB * NH * NCH, 256, 0, stream>>>(Q, K, V, Mtop, part);
        attn_merge_kernel<<<NB * NH * NTOP / 4, 256, 0, stream>>>(part, Mtop, ctx);
        cumsumA_kernel<<<NB * NH * 16, 256, 0, stream>>>(V, chunkSums);
        cumsumC_kernel<<<NB * NH * 16, 256, 0, stream>>>(V, chunkSums, out);
        scatter_kernel<<<NB * NH * NTOP / 4, 256, 0, stream>>>(ctx, Mtop, out);
    } else {
        cumsumA_kernel<<<NB * NH * 16, 256, 0, stream>>>(V, chunkSums);
        cumsumC_kernel<<<NB * NH * 16, 256, 0, stream>>>(V, chunkSums, out);
        attn_rows_kernel<<<NB * NH * NTOP, 256, 0, stream>>>(Q, K, V, Mtop, out);
    }
}

// Round 7
// 414.726 us; speedup vs baseline: 1.6556x; 1.0529x over previous
//
#include <hip/hip_runtime.h>

// Problem constants (B, L, H, D) = (4, 4096, 8, 64), FACTOR=5
#define NB 4
#define LSEQ 4096
#define NH 8
#define ND 64
#define NSAMP 45
#define NTOP 45
#define ACH 256            // keys per attention chunk
#define NCH (LSEQ / ACH)   // 16 chunks

typedef float f32x4 __attribute__((ext_vector_type(4)));

// ---------------------------------------------------------------------------
// Kernel 0 (prep): per l, bucket-sort the 45 (idx,s) pairs by 256-row chunk.
// UNCHANGED (r10).
// ---------------------------------------------------------------------------
__global__ __launch_bounds__(256) void prep_kernel(
        const int* __restrict__ idxS, int* __restrict__ sortedPack) {
    int t = threadIdx.x;
    int l = blockIdx.x * 256 + t;
    const int* is = idxS + (size_t)l * NSAMP;
    __shared__ int cnt[256][17];
    #pragma unroll
    for (int c = 0; c < 16; ++c) cnt[t][c] = 0;
    for (int s = 0; s < NSAMP; ++s) cnt[t][is[s] >> 8] += 1;
    int run = 0;
    #pragma unroll
    for (int c = 0; c < 16; ++c) { int v = cnt[t][c]; cnt[t][c] = run; run += v; }
    for (int s = 0; s < NSAMP; ++s) {
        int idx = is[s];
        int pos = cnt[t][idx >> 8]++;
        sortedPack[(size_t)l * NSAMP + pos] = (idx << 8) | s;
    }
}

// ---------------------------------------------------------------------------
// Kernel 1: M[b,h,l]. LDS-staged gather (r10 body), round-12 occupancy fix:
// 512 threads/block (8 waves = 2/SIMD, was 4 waves = 1/SIMD). The 161792 B
// LDS footprint is per-BLOCK, so doubling threads doubles resident waves at
// zero LDS cost. Each thread owns ONE l (q regs halve -> ~130 VGPR <= 256
// cap at 2 waves/SIMD, no spill). Arithmetic, sample order, and fold order
// byte-identical -> M bit-identical -> selection frozen.
// ---------------------------------------------------------------------------
__global__ __launch_bounds__(512, 1) void compute_M_kernel(
        const float* __restrict__ Q,
        const float* __restrict__ K,
        const int* __restrict__ sortedPack,
        float* __restrict__ Mout) {
    int xcd = blockIdx.x & 7;
    int sub = blockIdx.x >> 3;
    int bh  = (xcd << 2) | (sub & 3);      // 4 bh per XCD -> 4MB L2 K stream
    int lt  = sub >> 2;                    // 0..7 (512-l tile)
    int b = bh >> 3, h = bh & 7;
    int t = threadIdx.x;                   // 0..511
    int l0 = (lt << 9) + t;

    __shared__ float Ks[256 * 68];
    __shared__ float Plds[512 * 45];

    // Q row in regs (nontemporal: one-shot stream, keep L2 for K).
    f32x4 qa[16];
    {
        const f32x4* qp0 = reinterpret_cast<const f32x4*>(
            Q + (((size_t)b * LSEQ + l0) * NH + h) * ND);
        #pragma unroll
        for (int i = 0; i < 16; ++i) qa[i] = __builtin_nontemporal_load(qp0 + i);
    }

    // EXACT original tree: products, off=32 fused, then 16/8/4/2/1.
    auto dotQK = [&](const f32x4 (&q4)[16], const float* kr) -> float {
        const f32x4* k4 = reinterpret_cast<const f32x4*>(kr);
        float w[32];
        #pragma unroll
        for (int i = 0; i < 8; ++i) {
            f32x4 a = q4[i], bb = k4[i], c = q4[i + 8], d4 = k4[i + 8];
            w[4 * i + 0] = __fadd_rn(__fmul_rn(a.x, bb.x), __fmul_rn(c.x, d4.x));
            w[4 * i + 1] = __fadd_rn(__fmul_rn(a.y, bb.y), __fmul_rn(c.y, d4.y));
            w[4 * i + 2] = __fadd_rn(__fmul_rn(a.z, bb.z), __fmul_rn(c.z, d4.z));
            w[4 * i + 3] = __fadd_rn(__fmul_rn(a.w, bb.w), __fmul_rn(c.w, d4.w));
        }
        #pragma unroll
        for (int off = 16; off; off >>= 1) {
            #pragma unroll
            for (int i = 0; i < off; ++i) w[i] = __fadd_rn(w[i], w[i + off]);
        }
        return w[0];
    };

    const int* sp0 = sortedPack + (size_t)l0 * NSAMP;
    int ptr0 = 0;
    int pk0 = sp0[0];

    size_t kbh = ((size_t)b * LSEQ * NH + h) * ND;

    for (int c = 0; c < 16; ++c) {
        // stage rows [c*256, c*256+256): 4096 f32x4 over 512 threads = 8 ea.
        #pragma unroll
        for (int i = 0; i < 8; ++i) {
            int flat = i * 512 + t;
            int row = flat >> 4, col = flat & 15;
            f32x4 v = *reinterpret_cast<const f32x4*>(
                K + kbh + (size_t)(c * 256 + row) * (NH * ND) + col * 4);
            *reinterpret_cast<f32x4*>(&Ks[row * 68 + col * 4]) = v;
        }
        __syncthreads();

        while ((pk0 >> 16) == c) {
            int r = (pk0 >> 8) & 255;
            int s = pk0 & 255;
            Plds[t * 45 + s] = dotQK(qa, &Ks[r * 68]);
            ++ptr0;
            pk0 = (ptr0 < NSAMP) ? sp0[ptr0] : 0x7fffffff;
        }
        __syncthreads();
    }

    // Fold in ORIGINAL s order (thread reads only its own Plds entries).
    {
        float maxv = -INFINITY, sumv = 0.0f;
        for (int s = 0; s < NSAMP; ++s) {
            float v = Plds[t * 45 + s];
            maxv = fmaxf(maxv, v);
            sumv = __fadd_rn(sumv, v);
        }
        Mout[(size_t)bh * LSEQ + l0] = maxv - sumv * (1.0f / (float)LSEQ);
    }
}

// ---------------------------------------------------------------------------
// Kernel 2: top-45 per (b,h). UNCHANGED (selection semantics frozen).
// ---------------------------------------------------------------------------
__global__ __launch_bounds__(256) void topk_kernel(
        const float* __restrict__ M, int* __restrict__ Mtop) {
    int bh = blockIdx.x;
    int t = threadIdx.x;
    int wave = t >> 6, lane = t & 63;
    const float* m = M + (size_t)bh * LSEQ;

    float rv[16];
    #pragma unroll
    for (int k = 0; k < 16; ++k) rv[k] = m[t + (k << 8)];

    __shared__ float wv[4];
    __shared__ int   wi[4];
    __shared__ int   winIdx;

    for (int iter = 0; iter < NTOP; ++iter) {
        float bv = -INFINITY; int bi = 0x7fffffff;
        #pragma unroll
        for (int k = 0; k < 16; ++k) {
            float v = rv[k];
            if (v > bv) { bv = v; bi = t + (k << 8); }
        }
        #pragma unroll
        for (int off = 1; off < 64; off <<= 1) {
            float ov = __shfl_xor(bv, off, 64);
            int   oi = __shfl_xor(bi, off, 64);
            if (ov > bv || (ov == bv && oi < bi)) { bv = ov; bi = oi; }
        }
        if (lane == 0) { wv[wave] = bv; wi[wave] = bi; }
        __syncthreads();
        if (t == 0) {
            float cv = wv[0]; int ci = wi[0];
            for (int ww = 1; ww < 4; ++ww) {
                if (wv[ww] > cv || (wv[ww] == cv && wi[ww] < ci)) { cv = wv[ww]; ci = wi[ww]; }
            }
            winIdx = ci;
            Mtop[bh * NTOP + iter] = ci;
        }
        __syncthreads();
        int widx = winIdx;
        #pragma unroll
        for (int k = 0; k < 16; ++k)
            if (widx == t + (k << 8)) rv[k] = -INFINITY;
        __syncthreads();
    }
}

// ---------------------------------------------------------------------------
// Kernel 3a/3b: V cumsum. UNCHANGED.
// ---------------------------------------------------------------------------
__global__ __launch_bounds__(256) void cumsumA_kernel(
        const float* __restrict__ V, float* __restrict__ chunkSums) {
    int blk = blockIdx.x;
    int c = blk & 15;
    int bh = blk >> 4;
    int h = bh & (NH - 1);
    int b = bh >> 3;
    int g = threadIdx.x >> 6, d = threadIdx.x & 63;

    const size_t rstride = (size_t)NH * ND;
    size_t vbase = (size_t)b * LSEQ * rstride + (size_t)h * ND + d;

    int l0 = c * 256 + g * 64;
    float s = 0.0f;
    for (int l = l0; l < l0 + 64; ++l) s += V[vbase + (size_t)l * rstride];

    __shared__ float part[4][ND];
    part[g][d] = s;
    __syncthreads();
    if (threadIdx.x < ND)
        chunkSums[(size_t)blk * ND + d] =
            part[0][d] + part[1][d] + part[2][d] + part[3][d];
}

__global__ __launch_bounds__(256) void cumsumC_kernel(
        const float* __restrict__ V, const float* __restrict__ chunkSums,
        float* __restrict__ out) {
    int blk = blockIdx.x;
    int c = blk & 15;
    int bh = blk >> 4;
    int h = bh & (NH - 1);
    int b = bh >> 3;
    int g = threadIdx.x >> 6, d = threadIdx.x & 63;

    const size_t rstride = (size_t)NH * ND;
    size_t vbase = (size_t)b * LSEQ * rstride + (size_t)h * ND + d;

    float run = 0.0f;
    for (int cc = 0; cc < c; ++cc)
        run += chunkSums[((size_t)bh * 16 + cc) * ND + d];

    int l0 = c * 256 + g * 64;
    float s = 0.0f;
    for (int l = l0; l < l0 + 64; ++l) s += V[vbase + (size_t)l * rstride];
    __shared__ float part[4][ND];
    part[g][d] = s;
    __syncthreads();
    for (int gg = 0; gg < g; ++gg) run += part[gg][d];

    size_t obase = (size_t)bh * LSEQ * ND + d;
    for (int l = l0; l < l0 + 64; ++l) {
        run += V[vbase + (size_t)l * rstride];
        out[obase + (size_t)l * ND] = run;
    }
}

// ---------------------------------------------------------------------------
// Kernel 4: flash split-K attention (r11). UNCHANGED.
// ---------------------------------------------------------------------------
__global__ __launch_bounds__(256, 1) void attn_partial_kernel(
        const float* __restrict__ Q, const float* __restrict__ K,
        const float* __restrict__ V, const int* __restrict__ Mtop,
        float* __restrict__ part) {
    int bh = blockIdx.x >> 4;
    int c  = blockIdx.x & 15;
    int b = bh >> 3, h = bh & 7;
    int t = threadIdx.x;
    int w = t >> 6, lane = t & 63;
    int jj = lane >> 4, dq = lane & 15;

    __shared__ float Qs[NTOP * ND];
    __shared__ int   posS[NTOP];
    __shared__ float Vs[64][68];
    __shared__ float Pw[4][64];

    size_t base = ((size_t)b * LSEQ * NH + h) * ND;

    if (t < NTOP) posS[t] = Mtop[bh * NTOP + t];
    __syncthreads();
    for (int idx = t; idx < NTOP * 16; idx += 256) {
        int u = idx >> 4, cg = idx & 15;
        f32x4 v = *reinterpret_cast<const f32x4*>(
            Q + base + (size_t)posS[u] * (NH * ND) + cg * 4);
        *reinterpret_cast<f32x4*>(&Qs[u * ND + cg * 4]) = v;
    }

    f32x4 o[12];
    float mreg[12], sreg[12];
    #pragma unroll
    for (int qi = 0; qi < 12; ++qi) {
        o[qi] = 0.0f; mreg[qi] = -INFINITY; sreg[qi] = 0.0f;
    }

    for (int tt = 0; tt < ACH / 64; ++tt) {
        int tile0 = c * ACH + tt * 64;
        __syncthreads();
        #pragma unroll
        for (int i = 0; i < 4; ++i) {
            int flat = i * 256 + t;
            int r = flat >> 4, cg = flat & 15;
            f32x4 v = *reinterpret_cast<const f32x4*>(
                V + base + (size_t)(tile0 + r) * (NH * ND) + cg * 4);
            *reinterpret_cast<f32x4*>(&Vs[r][cg * 4]) = v;
        }
        __syncthreads();

        f32x4 kreg[16];
        #pragma unroll
        for (int i = 0; i < 16; ++i)
            kreg[i] = *reinterpret_cast<const f32x4*>(
                K + base + (size_t)(tile0 + lane) * (NH * ND) + i * 4);

        #pragma unroll
        for (int qi = 0; qi < 12; ++qi) {
            int u = w + 4 * qi;
            if (u >= NTOP) continue;
            int pu = posS[u];
            if (pu < tile0) continue;

            float a0 = 0, a1 = 0, a2 = 0, a3 = 0;
            #pragma unroll
            for (int di = 0; di < 16; ++di) {
                f32x4 qv = *reinterpret_cast<const f32x4*>(&Qs[u * ND + di * 4]);
                a0 = fmaf(qv.x, kreg[di].x, a0);
                a1 = fmaf(qv.y, kreg[di].y, a1);
                a2 = fmaf(qv.z, kreg[di].z, a2);
                a3 = fmaf(qv.w, kreg[di].w, a3);
            }
            float sc = ((a0 + a1) + (a2 + a3)) * 0.125f;
            if (tile0 + lane > pu) sc = -INFINITY;

            float tmax = sc;
            #pragma unroll
            for (int off = 1; off < 64; off <<= 1)
                tmax = fmaxf(tmax, __shfl_xor(tmax, off, 64));
            float mold = mreg[qi];
            float mnew = fmaxf(mold, tmax);
            float alpha = __expf(mold - mnew);
            float e = __expf(sc - mnew);
            float esum = e;
            #pragma unroll
            for (int off = 1; off < 64; off <<= 1)
                esum += __shfl_xor(esum, off, 64);
            sreg[qi] = sreg[qi] * alpha + esum;
            mreg[qi] = mnew;
            Pw[w][lane] = e;
            o[qi] *= alpha;
            #pragma unroll
            for (int i = 0; i < 16; ++i) {
                float pe = Pw[w][i * 4 + jj];
                f32x4 vv = *reinterpret_cast<const f32x4*>(&Vs[i * 4 + jj][dq * 4]);
                o[qi] += vv * pe;
            }
        }
    }

    #pragma unroll
    for (int qi = 0; qi < 12; ++qi) {
        int u = w + 4 * qi;
        if (u >= NTOP) continue;
        if (posS[u] < c * ACH) continue;
        f32x4 oo = o[qi];
        #pragma unroll
        for (int off = 16; off <= 32; off <<= 1) {
            oo.x += __shfl_xor(oo.x, off, 64);
            oo.y += __shfl_xor(oo.y, off, 64);
            oo.z += __shfl_xor(oo.z, off, 64);
            oo.w += __shfl_xor(oo.w, off, 64);
        }
        size_t pb = ((size_t)(bh * NTOP + u) * NCH + c) * 72;
        if (lane < 16)
            *reinterpret_cast<f32x4*>(&part[pb + 4 + dq * 4]) = oo;
        if (lane == 0) { part[pb] = mreg[qi]; part[pb + 1] = sreg[qi]; }
    }
}

// ---------------------------------------------------------------------------
// Kernel 5: merge chunk partials -> compact ctx. UNCHANGED.
// ---------------------------------------------------------------------------
__global__ __launch_bounds__(256) void attn_merge_kernel(
        const float* __restrict__ part, const int* __restrict__ Mtop,
        float* __restrict__ ctx) {
    int j = blockIdx.x * 4 + (threadIdx.x >> 6);
    int lane = threadIdx.x & 63;
    int bh = j / NTOP, u = j - bh * NTOP;
    int pos = Mtop[bh * NTOP + u];
    int cmax = pos >> 8;
    size_t pb0 = (size_t)(bh * NTOP + u) * NCH * 72;
    float m = -INFINITY;
    for (int cc = 0; cc <= cmax; ++cc)
        m = fmaxf(m, part[pb0 + (size_t)cc * 72]);
    float S = 0.0f, oacc = 0.0f;
    for (int cc = 0; cc <= cmax; ++cc) {
        float mc = part[pb0 + (size_t)cc * 72];
        float sc = part[pb0 + (size_t)cc * 72 + 1];
        float wgt = __expf(mc - m);
        S = fmaf(sc, wgt, S);
        oacc = fmaf(part[pb0 + (size_t)cc * 72 + 4 + lane], wgt, oacc);
    }
    ctx[(size_t)j * ND + lane] = oacc / S;
}

// ---------------------------------------------------------------------------
// Kernel 6: scatter ctx rows into out AFTER cumsum. UNCHANGED.
// ---------------------------------------------------------------------------
__global__ __launch_bounds__(256) void scatter_kernel(
        const float* __restrict__ ctx, const int* __restrict__ Mtop,
        float* __restrict__ out) {
    int j = blockIdx.x * 4 + (threadIdx.x >> 6);
    int lane = threadIdx.x & 63;
    int bh = j / NTOP, u = j - bh * NTOP;
    int pos = Mtop[bh * NTOP + u];
    out[((size_t)bh * LSEQ + pos) * ND + lane] = ctx[(size_t)j * ND + lane];
}

// ---------------------------------------------------------------------------
// Kernel 4-FALLBACK: old per-(bh,u) flash attention (r6). Used only if
// ws_size is too small for the compact ctx buffer.
// ---------------------------------------------------------------------------
#define TJ 64
__global__ __launch_bounds__(256) void attn_rows_kernel(
        const float* __restrict__ Q,
        const float* __restrict__ K,
        const float* __restrict__ V,
        const int* __restrict__ Mtop,
        float* __restrict__ out) {
    int x = blockIdx.x;
    int xcd = x & 7;
    int slot = x >> 3;
    int grp = slot / NTOP;
    int u = slot % NTOP;
    int bh = grp * 8 + xcd;
    int h = bh & (NH - 1);
    int b = bh >> 3;
    int pos = Mtop[bh * NTOP + u];
    int n = pos + 1;
    int t = threadIdx.x;
    int r = t >> 2, qt = t & 3;

    __shared__ float Ks[TJ][65];
    __shared__ float Vs[TJ][65];
    __shared__ float red[256];

    const size_t rstride = (size_t)NH * ND;
    size_t base = (size_t)b * LSEQ * rstride + (size_t)h * ND;

    float qreg[16];
    const float* qrow = Q + base + (size_t)pos * rstride + qt * 16;
    #pragma unroll
    for (int i = 0; i < 16; i += 4) {
        float4 v4 = *reinterpret_cast<const float4*>(qrow + i);
        qreg[i] = v4.x; qreg[i + 1] = v4.y; qreg[i + 2] = v4.z; qreg[i + 3] = v4.w;
    }

    float m = -INFINITY, s = 0.0f;
    float o[16];
    #pragma unroll
    for (int dd = 0; dd < 16; ++dd) o[dd] = 0.0f;

    int ntiles = (n + TJ - 1) / TJ;
    for (int tt = 0; tt < ntiles; ++tt) {
        int j0 = tt * TJ;
        __syncthreads();
        #pragma unroll
        for (int i = 0; i < 4; ++i) {
            int u16 = t + i * 256;
            int rr = u16 >> 4, cc = u16 & 15;
            int j = j0 + rr;
            int jc = (j < n) ? j : (n - 1);
            const float* rowk = K + base + (size_t)jc * rstride;
            float4 kv = *reinterpret_cast<const float4*>(rowk + cc * 4);
            Ks[rr][cc * 4 + 0] = kv.x; Ks[rr][cc * 4 + 1] = kv.y;
            Ks[rr][cc * 4 + 2] = kv.z; Ks[rr][cc * 4 + 3] = kv.w;
            const float* rowv = V + base + (size_t)jc * rstride;
            float4 vv = *reinterpret_cast<const float4*>(rowv + cc * 4);
            Vs[rr][cc * 4 + 0] = vv.x; Vs[rr][cc * 4 + 1] = vv.y;
            Vs[rr][cc * 4 + 2] = vv.z; Vs[rr][cc * 4 + 3] = vv.w;
        }
        __syncthreads();

        int j = j0 + r;
        float acc = 0.0f;
        #pragma unroll
        for (int dd = 0; dd < 16; ++dd)
            acc = fmaf(qreg[dd], Ks[r][qt * 16 + dd], acc);
        acc += __shfl_xor(acc, 1, 64);
        acc += __shfl_xor(acc, 2, 64);

        if (j < n) {
            float sc = acc * 0.125f;
            if (sc > m) {
                float alpha = __expf(m - sc);
                s *= alpha;
                #pragma unroll
                for (int dd = 0; dd < 16; ++dd) o[dd] *= alpha;
                m = sc;
            }
            float e = __expf(sc - m);
            s += e;
            #pragma unroll
            for (int dd = 0; dd < 16; ++dd)
                o[dd] = fmaf(e, Vs[r][qt * 16 + dd], o[dd]);
        }
    }
    __syncthreads();

    red[t] = m; __syncthreads();
    for (int sft = 128; sft; sft >>= 1) {
        if (t < sft) red[t] = fmaxf(red[t], red[t + sft]);
        __syncthreads();
    }
    float mstar = red[0]; __syncthreads();
    float a = __expf(m - mstar);

    red[t] = s * a; __syncthreads();
    for (int sft = 128; sft; sft >>= 1) {
        if (t < sft) red[t] += red[t + sft];
        __syncthreads();
    }
    float S = red[0]; __syncthreads();

    float* OB = &Ks[0][0];
    #pragma unroll
    for (int dd = 0; dd < 16; ++dd) OB[t * 16 + dd] = o[dd] * a;
    __syncthreads();

    if (t < ND) {
        int qtt = t >> 4, dd = t & 15;
        float tot = 0.0f;
        for (int k = 0; k < 64; ++k) tot += OB[(4 * k + qtt) * 16 + dd];
        out[((size_t)bh * LSEQ + pos) * ND + t] = tot / S;
    }
}

// ---------------------------------------------------------------------------
extern "C" void kernel_launch(void* const* d_in, const int* in_sizes, int n_in,
                              void* d_out, int out_size, void* d_ws, size_t ws_size,
                              hipStream_t stream) {
    const float* Q = (const float*)d_in[0];
    const float* K = (const float*)d_in[1];
    const float* V = (const float*)d_in[2];
    const int* idxS = (const int*)d_in[3];
    float* out = (float*)d_out;

    // d_out scratch (all consumed before cumsum overwrites):
    //   M       @ 0     (512 KB)  -> topk
    //   sorted  @ 1 MB  (737 KB)  -> compute_M
    //   part    @ 2 MB  (6.6 MB)  -> attn_merge
    // ws: Mtop (5760B) @0, chunkSums (128KB) @8192, ctx (360KB) @139264.
    float* Mbuf = (float*)d_out;
    int*   sortedPack = (int*)((char*)d_out + (1 << 20));
    float* part = (float*)((char*)d_out + (2 << 20));
    int*   Mtop = (int*)d_ws;
    float* chunkSums = (float*)((char*)d_ws + 8192);
    float* ctx = (float*)((char*)d_ws + 8192 + 131072);
    size_t wsNeeded = 8192 + 131072 + (size_t)NB * NH * NTOP * ND * 4;

    prep_kernel<<<LSEQ / 256, 256, 0, stream>>>(idxS, sortedPack);
    compute_M_kernel<<<256, 512, 0, stream>>>(Q, K, sortedPack, Mbuf);
    topk_kernel<<<NB * NH, 256, 0, stream>>>(Mbuf, Mtop);

    if (ws_size >= wsNeeded) {
        attn_partial_kernel<<<NB * NH * NCH, 256, 0, stream>>>(Q, K, V, Mtop, part);
        attn_merge_kernel<<<NB * NH * NTOP / 4, 256, 0, stream>>>(part, Mtop, ctx);
        cumsumA_kernel<<<NB * NH * 16, 256, 0, stream>>>(V, chunkSums);
        cumsumC_kernel<<<NB * NH * 16, 256, 0, stream>>>(V, chunkSums, out);
        scatter_kernel<<<NB * NH * NTOP / 4, 256, 0, stream>>>(ctx, Mtop, out);
    } else {
        cumsumA_kernel<<<NB * NH * 16, 256, 0, stream>>>(V, chunkSums);
        cumsumC_kernel<<<NB * NH * 16, 256, 0, stream>>>(V, chunkSums, out);
        attn_rows_kernel<<<NB * NH * NTOP, 256, 0, stream>>>(Q, K, V, Mtop, out);
    }
}